// Round 15
// baseline (750.150 us; speedup 1.0000x reference)
//
#include <hip/hip_runtime.h>
#include <stdint.h>

// ---------- common types / helpers ----------
typedef __attribute__((ext_vector_type(8))) short bf8;   // 8 x bf16 (4 VGPRs)
typedef __attribute__((ext_vector_type(4))) float f4;    // MFMA accumulator

__device__ __forceinline__ float bf2f(uint16_t u) {
  union { unsigned i; float f; } v; v.i = ((unsigned)u) << 16; return v.f;
}
__device__ __forceinline__ uint16_t f2bf(float f) {
  union { float f; unsigned i; } v; v.f = f;
  unsigned r = v.i + 0x7fffu + ((v.i >> 16) & 1u);   // RTNE
  return (uint16_t)(r >> 16);
}
__device__ __forceinline__ bf8 cvt8(float4 a, float4 b) {
  bf8 r;
  r[0]=(short)f2bf(a.x); r[1]=(short)f2bf(a.y); r[2]=(short)f2bf(a.z); r[3]=(short)f2bf(a.w);
  r[4]=(short)f2bf(b.x); r[5]=(short)f2bf(b.y); r[6]=(short)f2bf(b.z); r[7]=(short)f2bf(b.w);
  return r;
}
// packed f32x2 -> bf16x2 (RNE); dst.lo = cvt(a), dst.hi = cvt(b)  [T12 recipe]
__device__ __forceinline__ uint32_t cvtpk(float a, float b) {
  uint32_t r;
  asm("v_cvt_pk_bf16_f32 %0, %1, %2" : "=v"(r) : "v"(a), "v"(b));
  return r;
}

// async global->LDS, 16B per lane, wave-uniform LDS base + lane*16
__device__ __forceinline__ void gload_lds16(const void* g, void* l) {
  __builtin_amdgcn_global_load_lds(
      (const __attribute__((address_space(1))) uint32_t*)(uintptr_t)g,
      (__attribute__((address_space(3))) uint32_t*)(uint32_t)(uintptr_t)l,
      16, 0, 0);
}

// ---------- f32 -> bf16 bulk convert ----------
__global__ __launch_bounds__(256)
void eagle3_cvt(const float* __restrict__ src, uint16_t* __restrict__ dst, int n8)
{
  int i = blockIdx.x * 256 + threadIdx.x;
  const int stride = gridDim.x * 256;
  for (; i < n8; i += stride) {
    const float4 a = ((const float4*)src)[i * 2];
    const float4 b = ((const float4*)src)[i * 2 + 1];
    ((bf8*)dst)[i] = cvt8(a, b);
  }
}

// ---------- triple f32 -> bf16 convert (Wk, Wv, Wo in one launch) ----------
__global__ __launch_bounds__(256)
void eagle3_cvt3(const float* __restrict__ s1, uint16_t* __restrict__ d1, int n1,
                 const float* __restrict__ s2, uint16_t* __restrict__ d2, int n2,
                 const float* __restrict__ s3, uint16_t* __restrict__ d3, int n3)
{
  int i = blockIdx.x * 256 + threadIdx.x;
  const int stride = gridDim.x * 256;
  const int tot = n1 + n2 + n3;
  for (; i < tot; i += stride) {
    const float* src; uint16_t* dst; int j;
    if (i < n1)           { src = s1; dst = d1; j = i; }
    else if (i < n1 + n2) { src = s2; dst = d2; j = i - n1; }
    else                  { src = s3; dst = d3; j = i - n1 - n2; }
    const float4 a = ((const float4*)src)[j * 2];
    const float4 b = ((const float4*)src)[j * 2 + 1];
    ((bf8*)dst)[j] = cvt8(a, b);
  }
}

// ---------- GEMM KV (128x128 m97 structure, N=2048, fused K-RoPE) ----------
// B = [Wk;Wv] bf16 [2048, 8192]; blocks with n0 < 1024 compute K (one full
// head per block: cols = head h = c0/128) and apply RoPE in the epilogue via
// a 128x128 bf16 LDS stash (pair (d, d+64) spans two waves); n0 >= 1024
// blocks write V plainly. Numerics of the fused rope == old standalone kernel
// (same bf16 roundtrip of the projected K before the rotation).
__global__ __launch_bounds__(256)
void eagle3_gemmkv(const uint16_t* __restrict__ Ap, const uint16_t* __restrict__ Bp,
                   uint16_t* __restrict__ Kc, uint16_t* __restrict__ Vc,
                   const float* __restrict__ Cst, const float* __restrict__ Snt)
{
  __shared__ __align__(16) uint16_t As[128 * 32];
  __shared__ __align__(16) uint16_t Bs[128 * 32];
  __shared__ __align__(16) uint16_t Kx[128 * 130];   // K-rope stash (pad 2)
  const int K = 8192, lda = 8192, ldb = 8192;

  const int nwg = gridDim.x * gridDim.y;
  const int bid = blockIdx.y * gridDim.x + blockIdx.x;
  const int qq = nwg >> 3;
  const int sw = (bid & 7) * qq + (bid >> 3);
  const int bx = sw % gridDim.x, by = sw / gridDim.x;
  const int m0 = by * 128, n0 = bx * 128;

  const int tid = threadIdx.x, lane = tid & 63, w = tid >> 6;
  const int tl = lane & 15, g = lane >> 4;
  const int wr = (w >> 1) * 64, wc = (w & 1) * 64;

  f4 acc[4][4] = {};

  for (int k0 = 0; k0 < K; k0 += 32) {
    __syncthreads();
    #pragma unroll
    for (int i = 0; i < 2; ++i) {
      const int o = (w * 2 + i) * 1024 + lane * 16;
      const int r = o >> 6;
      const int u = (((o >> 4) & 3) ^ ((r >> 1) & 3)) * 8;
      gload_lds16(Ap + (size_t)(m0 + r) * lda + k0 + u, &As[(w * 2 + i) * 512]);
    }
    #pragma unroll
    for (int i = 0; i < 2; ++i) {
      const int o = (w * 2 + i) * 1024 + lane * 16;
      const int r = o >> 6;
      const int u = (((o >> 4) & 3) ^ ((r >> 1) & 3)) * 8;
      gload_lds16(Bp + (size_t)(n0 + r) * ldb + k0 + u, &Bs[(w * 2 + i) * 512]);
    }
    __syncthreads();

    bf8 af[4], bf_[4];
    #pragma unroll
    for (int i = 0; i < 4; ++i) {
      const int ar = wr + i * 16 + tl;
      const int br = wc + i * 16 + tl;
      af[i]  = *(const bf8*)&As[ar * 32 + ((g ^ ((ar >> 1) & 3)) * 8)];
      bf_[i] = *(const bf8*)&Bs[br * 32 + ((g ^ ((br >> 1) & 3)) * 8)];
    }
    #pragma unroll
    for (int mi = 0; mi < 4; ++mi)
      #pragma unroll
      for (int ni = 0; ni < 4; ++ni)
        acc[mi][ni] = __builtin_amdgcn_mfma_f32_16x16x32_bf16(af[mi], bf_[ni], acc[mi][ni], 0, 0, 0);
  }

  const bool isK = (n0 < 1024);        // block-uniform
  const int c0 = n0 & 1023;
  if (isK) {
    // stash bf16 K tile (full head: local col 0..127 == d)
    #pragma unroll
    for (int mi = 0; mi < 4; ++mi)
      #pragma unroll
      for (int r = 0; r < 4; ++r) {
        const int row = wr + mi * 16 + g * 4 + r;
        #pragma unroll
        for (int ni = 0; ni < 4; ++ni)
          Kx[row * 130 + wc + ni * 16 + tl] = f2bf(acc[mi][ni][r]);
      }
    __syncthreads();
    // rope: out_d = x_d*c - x_{d^64}*s (d<64) / + (d>=64); wc-uniform sign
    #pragma unroll
    for (int mi = 0; mi < 4; ++mi)
      #pragma unroll
      for (int r = 0; r < 4; ++r) {
        const int row = wr + mi * 16 + g * 4 + r;
        const int s = (m0 + row) & 2047;
        #pragma unroll
        for (int ni = 0; ni < 4; ++ni) {
          const int d = wc + ni * 16 + tl;
          const float own = bf2f(Kx[row * 130 + d]);
          const float oth = bf2f(Kx[row * 130 + (d ^ 64)]);
          const float cv = Cst[s * 128 + d];
          const float sv = Snt[s * 128 + d];
          const float out = wc ? (own * cv + oth * sv) : (own * cv - oth * sv);
          Kc[(size_t)(m0 + row) * 1024 + c0 + d] = f2bf(out);
        }
      }
  } else {
    #pragma unroll
    for (int mi = 0; mi < 4; ++mi)
      #pragma unroll
      for (int r = 0; r < 4; ++r) {
        const int row = m0 + wr + mi * 16 + g * 4 + r;
        #pragma unroll
        for (int ni = 0; ni < 4; ++ni) {
          const int col = c0 + wc + ni * 16 + tl;
          Vc[(size_t)row * 1024 + col] = f2bf(acc[mi][ni][r]);
        }
      }
  }
}

// ---------- GEMM v5 (256x256, BK=64, 8-phase schedule) — unchanged ----------
template<bool OF32>
__global__ __launch_bounds__(512, 2)
void eagle3_gemm5(const uint16_t* __restrict__ Ap, const uint16_t* __restrict__ Bp,
                  void* __restrict__ Cp, int K, int lda, int ldb, int ldc)
{
  __shared__ __align__(16) uint16_t As[2][2][128 * 64];
  __shared__ __align__(16) uint16_t Bs[2][2][128 * 64];

  int bx, by;
  const int bid = blockIdx.y * gridDim.x + blockIdx.x;
  if (gridDim.x == 16 && gridDim.y == 16) {
    const int x = bid & 7, j = bid >> 3;
    by = (x >> 1) * 4 + (j >> 3);
    bx = (x & 1) * 8 + (j & 7);
  } else {
    const int nwg = gridDim.x * gridDim.y;
    const int qq = nwg >> 3;
    const int sw = (bid & 7) * qq + (bid >> 3);
    bx = sw % gridDim.x; by = sw / gridDim.x;
  }
  const int m0 = by * 256, n0 = bx * 256;

  const int tid = threadIdx.x, lane = tid & 63;
  const int tl = lane & 15, g = lane >> 4;
  const int w = tid >> 6;
  const int wm = w >> 2, wn = w & 3;
  const int bhf = wn >> 1;
  const int bl0 = (wn & 1) * 64;

  f4 acc[8][4] = {};
  const int NI = K >> 7;

  const int jr = tid >> 3;
  const int jc = ((tid & 7) ^ (jr & 7)) * 8;
  #define STG_A(slot, h, tt)                                                    \
    { const int kk_ = (tt) << 6;                                                \
      gload_lds16(Ap + (size_t)(m0 + (h)*128 + jr) * lda + kk_ + jc,            \
                  &As[slot][h][tid * 8]);                                       \
      gload_lds16(Ap + (size_t)(m0 + (h)*128 + 64 + jr) * lda + kk_ + jc,       \
                  &As[slot][h][(tid + 512) * 8]); }
  #define STG_B(slot, h, tt)                                                    \
    { const int kk_ = (tt) << 6;                                                \
      gload_lds16(Bp + (size_t)(n0 + (h)*128 + jr) * ldb + kk_ + jc,            \
                  &Bs[slot][h][tid * 8]);                                       \
      gload_lds16(Bp + (size_t)(n0 + (h)*128 + 64 + jr) * ldb + kk_ + jc,       \
                  &Bs[slot][h][(tid + 512) * 8]); }

  const int rk0 = ((0 + g) ^ (tl & 7)) * 8;
  const int rk1 = ((4 + g) ^ (tl & 7)) * 8;

  bf8 af[8], b0[4], b1[4];
  #define READ_A(slot, rh)                                                      \
    { _Pragma("unroll")                                                         \
      for (int m_ = 0; m_ < 4; ++m_) {                                          \
        const int R_ = (rh)*64 + m_*16 + tl;                                    \
        af[m_*2]   = *(const bf8*)&As[slot][wm][R_*64 + rk0];                   \
        af[m_*2+1] = *(const bf8*)&As[slot][wm][R_*64 + rk1];                   \
      } }
  #define READ_B(slot, ch, dst)                                                 \
    { _Pragma("unroll")                                                         \
      for (int c_ = 0; c_ < 2; ++c_) {                                          \
        const int R_ = bl0 + (ch)*32 + c_*16 + tl;                              \
        dst[c_*2]   = *(const bf8*)&Bs[slot][bhf][R_*64 + rk0];                 \
        dst[c_*2+1] = *(const bf8*)&Bs[slot][bhf][R_*64 + rk1];                 \
      } }
  #define MID_SYNC                                                              \
    __builtin_amdgcn_sched_barrier(0);                                          \
    __builtin_amdgcn_s_barrier();                                               \
    asm volatile("s_waitcnt lgkmcnt(0)" ::: "memory");                          \
    __builtin_amdgcn_sched_barrier(0);
  #define CLOSE_BAR                                                             \
    __builtin_amdgcn_sched_barrier(0);                                          \
    __builtin_amdgcn_s_barrier();                                               \
    __builtin_amdgcn_sched_barrier(0);
  #define MFMA16(rh, ch, bsrc)                                                  \
    { __builtin_amdgcn_s_setprio(1);                                            \
      _Pragma("unroll")                                                         \
      for (int m_ = 0; m_ < 4; ++m_) {                                          \
        _Pragma("unroll")                                                       \
        for (int c_ = 0; c_ < 2; ++c_) {                                        \
          acc[(rh)*4+m_][(ch)*2+c_] = __builtin_amdgcn_mfma_f32_16x16x32_bf16(  \
              af[m_*2],   bsrc[c_*2],   acc[(rh)*4+m_][(ch)*2+c_], 0, 0, 0);    \
          acc[(rh)*4+m_][(ch)*2+c_] = __builtin_amdgcn_mfma_f32_16x16x32_bf16(  \
              af[m_*2+1], bsrc[c_*2+1], acc[(rh)*4+m_][(ch)*2+c_], 0, 0, 0);    \
        } }                                                                     \
      __builtin_amdgcn_s_setprio(0); }

  STG_A(0, 0, 0); STG_A(0, 1, 0); STG_B(0, 0, 0); STG_B(0, 1, 0);
  STG_B(1, 0, 1); STG_B(1, 1, 1);
  asm volatile("s_waitcnt vmcnt(4)" ::: "memory");
  CLOSE_BAR;
  READ_B(0, 0, b0);

  for (int i = 0; i < NI; ++i) {
    const int T1 = 2 * i + 1;
    const bool more = (i + 1 < NI);

    READ_A(0, 0);
    STG_A(1, 0, T1);
    MID_SYNC; MFMA16(0, 0, b0); CLOSE_BAR;

    READ_B(0, 1, b1);
    STG_A(1, 1, T1);
    MID_SYNC; MFMA16(0, 1, b1); CLOSE_BAR;

    READ_A(0, 1);
    if (more) STG_B(0, 0, T1 + 1);
    MID_SYNC; MFMA16(1, 0, b0);
    if (more) { asm volatile("s_waitcnt vmcnt(6)" ::: "memory"); }
    else      { asm volatile("s_waitcnt vmcnt(4)" ::: "memory"); }
    CLOSE_BAR;

    READ_B(1, 0, b0);
    if (more) STG_B(0, 1, T1 + 1);
    MID_SYNC; MFMA16(1, 1, b1);
    if (more) { asm volatile("s_waitcnt vmcnt(4)" ::: "memory"); }
    else      { asm volatile("s_waitcnt vmcnt(0)" ::: "memory"); }
    CLOSE_BAR;

    READ_A(1, 0);
    if (more) STG_A(0, 0, T1 + 1);
    MID_SYNC; MFMA16(0, 0, b0); CLOSE_BAR;

    READ_B(1, 1, b1);
    if (more) STG_A(0, 1, T1 + 1);
    MID_SYNC; MFMA16(0, 1, b1); CLOSE_BAR;

    READ_A(1, 1);
    if (more) STG_B(1, 0, T1 + 2);
    MID_SYNC; MFMA16(1, 0, b0);
    if (more) { asm volatile("s_waitcnt vmcnt(6)" ::: "memory"); }
    CLOSE_BAR;

    if (more) { READ_B(0, 0, b0); STG_B(1, 1, T1 + 2); }
    MID_SYNC; MFMA16(1, 1, b1);
    if (more) { asm volatile("s_waitcnt vmcnt(4)" ::: "memory"); }
    CLOSE_BAR;
  }
  #undef STG_A
  #undef STG_B
  #undef READ_A
  #undef READ_B
  #undef MID_SYNC
  #undef CLOSE_BAR
  #undef MFMA16

  const int wr = wm * 128, wc = wn * 64;
  #pragma unroll
  for (int mi = 0; mi < 8; ++mi) {
    #pragma unroll
    for (int r = 0; r < 4; ++r) {
      const int row = m0 + wr + mi * 16 + g * 4 + r;
      #pragma unroll
      for (int ni = 0; ni < 4; ++ni) {
        const int col = n0 + wc + ni * 16 + tl;
        const float v = acc[mi][ni][r];
        if constexpr (OF32) ((float*)Cp)[(size_t)row * ldc + col] = v;
        else                ((uint16_t*)Cp)[(size_t)row * ldc + col] = f2bf(v);
      }
    }
  }
}

// ---------- V transpose: [b,t,h,d] -> [b,h,d,t] ----------
__global__ __launch_bounds__(256)
void eagle3_vtrans(const uint16_t* __restrict__ V, uint16_t* __restrict__ Vt)
{
  __shared__ uint16_t T[64 * 136];
  const int tid = threadIdx.x;
  const int t0 = blockIdx.x * 64;
  const int bh = blockIdx.y;
  const int b = bh >> 3, h = bh & 7;
  {
    const int r = tid >> 2, c0 = (tid & 3) * 32;
    const uint16_t* src = V + (size_t)(b * 2048 + t0 + r) * 1024 + h * 128 + c0;
    #pragma unroll
    for (int j = 0; j < 4; ++j)
      *(bf8*)&T[r * 136 + c0 + j * 8] = *(const bf8*)(src + j * 8);
  }
  __syncthreads();
  {
    const int d = tid >> 1, tc = (tid & 1) * 32;
    uint16_t* dst = Vt + ((size_t)bh * 128 + d) * 2048 + t0 + tc;
    #pragma unroll
    for (int cc = 0; cc < 4; ++cc) {
      bf8 v;
      #pragma unroll
      for (int j = 0; j < 8; ++j) v[j] = T[(tc + cc * 8 + j) * 136 + d];
      *(bf8*)&dst[cc * 8] = v;
    }
  }
}

// ---------- causal GQA flash attention v7 (unchanged) ----------
__global__ __launch_bounds__(512, 4)
void eagle3_flash7(const uint16_t* __restrict__ Q, const uint16_t* __restrict__ Kt,
                   const uint16_t* __restrict__ Vt, uint16_t* __restrict__ O,
                   const float* __restrict__ Cst, const float* __restrict__ Snt)
{
  __shared__ __align__(16) uint16_t Ks[2][64 * 128];   // 32 KB
  __shared__ __align__(16) uint16_t Vs[2][128 * 64];   // 32 KB
  __shared__ __align__(16) uint16_t Pl[8][16 * 64];    // 16 KB (per-wave, swz)

  const int tid = threadIdx.x, lane = tid & 63, w = tid >> 6;
  const int tl = lane & 15, g = lane >> 4;

  const int bid = (int)blockIdx.x + ((int)blockIdx.y << 4) + ((int)blockIdx.z << 9);
  const int xcd = bid & 7, idx = bid >> 3;
  const int grp = xcd * 2 + (idx >> 6);
  const int j   = idx & 63;
  const int b = grp >> 3, hkv = grp & 7;
  const int hq = hkv * 4 + (j & 3);
  const int qt = 15 - (j >> 2);
  const int qrow0 = qt * 128 + w * 16;
  const int ntb = 2 * qt + 2;

  bf8 qf[4];
  {
    const int srow = qrow0 + tl;
    const uint16_t* qp = Q + ((size_t)(b * 2048 + srow)) * 4096 + hq * 128 + g * 8;
    #pragma unroll
    for (int kb = 0; kb < 4; ++kb) qf[kb] = *(const bf8*)(qp + kb * 32);
    const float* cp = Cst + (size_t)srow * 128 + g * 8;
    const float* sp = Snt + (size_t)srow * 128 + g * 8;
    #pragma unroll
    for (int kb = 0; kb < 2; ++kb) {
      const float4 c0 = *(const float4*)(cp + kb * 32);
      const float4 c1 = *(const float4*)(cp + kb * 32 + 4);
      const float4 s0 = *(const float4*)(sp + kb * 32);
      const float4 s1 = *(const float4*)(sp + kb * 32 + 4);
      const float cc[8] = {c0.x,c0.y,c0.z,c0.w,c1.x,c1.y,c1.z,c1.w};
      const float ss[8] = {s0.x,s0.y,s0.z,s0.w,s1.x,s1.y,s1.z,s1.w};
      #pragma unroll
      for (int e = 0; e < 8; ++e) {
        const float x1 = bf2f((uint16_t)qf[kb][e]);
        const float x2 = bf2f((uint16_t)qf[kb + 2][e]);
        qf[kb][e]     = (short)f2bf(x1 * cc[e] - x2 * ss[e]);
        qf[kb + 2][e] = (short)f2bf(x2 * cc[e] + x1 * ss[e]);
      }
    }
  }

  const uint16_t* Kbase = Kt + (size_t)b * 2048 * 1024 + hkv * 128;
  const uint16_t* Vtb   = Vt + ((size_t)(b * 8 + hkv) * 128) * 2048;

  bf8 onesf = {};
  if (tl == 0) {
    #pragma unroll
    for (int q8 = 0; q8 < 8; ++q8) onesf[q8] = (short)0x3F80;
  }

  f4 acc[8] = {};
  f4 accl = {};
  float rm[4] = {-3e38f, -3e38f, -3e38f, -3e38f};
  const float KS = 0.1275174f;                // log2(e)/sqrt(128)

  #define STAGE_TILE(buf, t0s)                                                   \
    {                                                                            \
      _Pragma("unroll")                                                          \
      for (int i = 0; i < 2; ++i) {                                              \
        const int f = i * 512 + tid;                                             \
        const int r = f >> 4, c = f & 15;                                        \
        gload_lds16(Kbase + (size_t)((t0s) + r) * 1024 + ((c ^ (r & 7)) * 8),    \
                    &Ks[buf][(i * 512 + w * 64) * 8]);                           \
      }                                                                          \
      _Pragma("unroll")                                                          \
      for (int i = 0; i < 2; ++i) {                                              \
        const int f = i * 512 + tid;                                             \
        const int d = f >> 3, c = f & 7;                                         \
        gload_lds16(Vtb + (size_t)d * 2048 + (t0s) + ((c ^ (d & 7)) * 8),        \
                    &Vs[buf][(i * 512 + w * 64) * 8]);                           \
      }                                                                          \
    }

  STAGE_TILE(0, 0);

  for (int tb = 0; tb < ntb; ++tb) {
    const int cur = tb & 1;
    const int t0 = tb * 64;

    if (tb + 1 < ntb) {
      STAGE_TILE(cur ^ 1, t0 + 64);
      asm volatile("s_waitcnt vmcnt(4)" ::: "memory");
    } else {
      asm volatile("s_waitcnt vmcnt(0)" ::: "memory");
    }
    __builtin_amdgcn_sched_barrier(0);
    __builtin_amdgcn_s_barrier();

    const bool active = (t0 <= qrow0 + 15);
    if (active) {
      f4 s[4] = {};
      __builtin_amdgcn_s_setprio(1);
      #pragma unroll
      for (int cf = 0; cf < 4; ++cf) {
        #pragma unroll
        for (int kb = 0; kb < 4; ++kb) {
          const bf8 kf = *(const bf8*)&Ks[cur][(cf * 16 + tl) * 128 +
                                              (((kb * 4 + g) ^ (tl & 7)) * 8)];
          s[cf] = __builtin_amdgcn_mfma_f32_16x16x32_bf16(qf[kb], kf, s[cf], 0, 0, 0);
        }
      }
      __builtin_amdgcn_s_setprio(0);

      const bool edge = (t0 + 63 > qrow0);
      float p[4][4];
      #pragma unroll
      for (int r = 0; r < 4; ++r) {
        float v[4];
        #pragma unroll
        for (int cf = 0; cf < 4; ++cf) v[cf] = s[cf][r];
        if (edge) {
          const int qg = qrow0 + g * 4 + r;
          #pragma unroll
          for (int cf = 0; cf < 4; ++cf)
            if (t0 + cf * 16 + tl > qg) v[cf] = -3e38f;
        }
        float mx = fmaxf(fmaxf(v[0], v[1]), fmaxf(v[2], v[3]));
        mx = fmaxf(mx, __shfl_xor(mx, 1));
        mx = fmaxf(mx, __shfl_xor(mx, 2));
        mx = fmaxf(mx, __shfl_xor(mx, 4));
        mx = fmaxf(mx, __shfl_xor(mx, 8));
        if (mx > rm[r]) {
          const float corr = exp2f((rm[r] - mx) * KS);
          #pragma unroll
          for (int df = 0; df < 8; ++df) acc[df][r] *= corr;
          accl[r] *= corr;
          rm[r] = mx;
        }
        #pragma unroll
        for (int cf = 0; cf < 4; ++cf) p[r][cf] = exp2f((v[cf] - rm[r]) * KS);
      }

      #pragma unroll
      for (int r = 0; r < 4; ++r) {
        const uint32_t pk0 = cvtpk(p[r][0], p[r][1]);
        const uint32_t pk1 = cvtpk(p[r][2], p[r][3]);
        const int row = g * 4 + r;
        const int sw = row & 7;
        uint16_t* Pw = &Pl[w][row * 64 + (tl & 7)];
        Pw[(((tl >> 3) + 0) ^ sw) * 8] = (uint16_t)pk0;
        Pw[(((tl >> 3) + 2) ^ sw) * 8] = (uint16_t)(pk0 >> 16);
        Pw[(((tl >> 3) + 4) ^ sw) * 8] = (uint16_t)pk1;
        Pw[(((tl >> 3) + 6) ^ sw) * 8] = (uint16_t)(pk1 >> 16);
      }
      const bf8 pf0 = *(const bf8*)&Pl[w][tl * 64 + ((g ^ (tl & 7)) * 8)];
      const bf8 pf1 = *(const bf8*)&Pl[w][tl * 64 + (((4 + g) ^ (tl & 7)) * 8)];

      __builtin_amdgcn_s_setprio(1);
      accl = __builtin_amdgcn_mfma_f32_16x16x32_bf16(pf0, onesf, accl, 0, 0, 0);
      accl = __builtin_amdgcn_mfma_f32_16x16x32_bf16(pf1, onesf, accl, 0, 0, 0);
      #pragma unroll
      for (int df = 0; df < 8; ++df) {
        const int vrow = (df * 16 + tl) * 64;
        const bf8 v0 = *(const bf8*)&Vs[cur][vrow + ((g ^ (tl & 7)) * 8)];
        const bf8 v1 = *(const bf8*)&Vs[cur][vrow + (((4 + g) ^ (tl & 7)) * 8)];
        acc[df] = __builtin_amdgcn_mfma_f32_16x16x32_bf16(pf0, v0, acc[df], 0, 0, 0);
        acc[df] = __builtin_amdgcn_mfma_f32_16x16x32_bf16(pf1, v1, acc[df], 0, 0, 0);
      }
      __builtin_amdgcn_s_setprio(0);
    }

    __builtin_amdgcn_s_barrier();
  }
  #undef STAGE_TILE

  #pragma unroll
  for (int r = 0; r < 4; ++r) {
    const float l = __shfl(accl[r], lane & 48);
    const float inv = 1.0f / l;
    const size_t ob = ((size_t)(b * 2048 + qrow0 + g * 4 + r)) * 4096 + hq * 128 + tl;
    #pragma unroll
    for (int df = 0; df < 8; ++df)
      O[ob + df * 16] = f2bf(acc[df][r] * inv);
  }
}

// ---------- launch ----------
extern "C" void kernel_launch(void* const* d_in, const int* in_sizes, int n_in,
                              void* d_out, int out_size, void* d_ws, size_t ws_size,
                              hipStream_t stream) {
  const float* hs   = (const float*)d_in[0];
  const float* cosT = (const float*)d_in[2];
  const float* sinT = (const float*)d_in[3];
  const float* Wq   = (const float*)d_in[4];
  const float* Wk   = (const float*)d_in[5];
  const float* Wv   = (const float*)d_in[6];
  const float* Wo   = (const float*)d_in[7];

  // ---- workspace liveness (ws >= 112 MiB, proven rounds 8-14) ----
  // hsb = d_out [4096,8192] bf16 (64MB)       live: cvt -> KV gemm
  // [  0M, 32M) qb     live: Q gemm -> flash
  // [ 32M, 40M) kbuf   live: KV gemm (rope fused) -> flash
  // [ 40M, 48M) vbuf   live: KV gemm -> vtrans
  // [ 48M,112M) Wq bf16 (dead after Q gemm); then [Wk;Wv] at [48M,80M)
  // [ 80M,112M) Wo bf16  live: cvt3 -> Wo gemm (over dead Wq tail)
  // [ 72M, 80M) vt     live: vtrans -> flash (over dead wkv tail)
  // [ 40M, 72M) ctx    live: flash -> Wo gemm (over dead bufs)
  char* ws = (char*)d_ws;
  uint16_t* qb   = (uint16_t*)(ws);
  uint16_t* kbuf = (uint16_t*)(ws + 33554432);
  uint16_t* vbuf = (uint16_t*)(ws + 41943040);
  uint16_t* wkv  = (uint16_t*)(ws + 50331648);
  uint16_t* vt   = (uint16_t*)(ws + 75497472);
  uint16_t* ctx  = (uint16_t*)(ws + 41943040);
  uint16_t* wobf = (uint16_t*)(ws + 83886080);
  uint16_t* hsb  = (uint16_t*)d_out;

  const dim3 blk(256);

  // 1) hs f32 -> bf16 (once)
  eagle3_cvt<<<dim3(2048), blk, 0, stream>>>(hs, hsb, 4194304);

  // 2) Q projection (Wq bf16 at [48M,112M), dead after this gemm)
  eagle3_cvt<<<dim3(2048), blk, 0, stream>>>(Wq, wkv, 4194304);
  eagle3_gemm5<false><<<dim3(16, 16), dim3(512), 0, stream>>>(
      hsb, wkv, (void*)qb, 8192, 8192, 8192, 4096);

  // 3) remaining weights in ONE cvt: [Wk;Wv] -> [48M,80M), Wo -> [80M,112M)
  eagle3_cvt3<<<dim3(2048), blk, 0, stream>>>(
      Wk, wkv, 1048576, Wv, wkv + 8388608, 1048576, Wo, wobf, 2097152);

  // 4) fused K/V projection (+in-epilogue RoPE on K) -> kbuf, vbuf
  eagle3_gemmkv<<<dim3(16, 32), blk, 0, stream>>>(
      hsb, wkv, kbuf, vbuf, cosT, sinT);

  // 5) V transpose
  eagle3_vtrans<<<dim3(32, 16), blk, 0, stream>>>(vbuf, vt);

  // 6) causal GQA flash attention (with in-register Q RoPE) -> ctx
  eagle3_flash7<<<dim3(16, 32, 2), dim3(512), 0, stream>>>(
      qb, kbuf, vt, ctx, cosT, sinT);

  // 7) output projection: out = ctx * Wo^T (f32 out over dead hsb)
  eagle3_gemm5<true><<<dim3(16, 16), dim3(512), 0, stream>>>(
      ctx, wobf, d_out, 4096, 4096, 4096, 4096);
}

// Round 16
// 740.563 us; speedup vs baseline: 1.0129x; 1.0129x over previous
//
#include <hip/hip_runtime.h>
#include <stdint.h>

// ---------- common types / helpers ----------
typedef __attribute__((ext_vector_type(8))) short bf8;   // 8 x bf16 (4 VGPRs)
typedef __attribute__((ext_vector_type(4))) float f4;    // MFMA accumulator

__device__ __forceinline__ float bf2f(uint16_t u) {
  union { unsigned i; float f; } v; v.i = ((unsigned)u) << 16; return v.f;
}
__device__ __forceinline__ uint16_t f2bf(float f) {
  union { float f; unsigned i; } v; v.f = f;
  unsigned r = v.i + 0x7fffu + ((v.i >> 16) & 1u);   // RTNE
  return (uint16_t)(r >> 16);
}
__device__ __forceinline__ bf8 cvt8(float4 a, float4 b) {
  bf8 r;
  r[0]=(short)f2bf(a.x); r[1]=(short)f2bf(a.y); r[2]=(short)f2bf(a.z); r[3]=(short)f2bf(a.w);
  r[4]=(short)f2bf(b.x); r[5]=(short)f2bf(b.y); r[6]=(short)f2bf(b.z); r[7]=(short)f2bf(b.w);
  return r;
}
// packed f32x2 -> bf16x2 (RNE); dst.lo = cvt(a), dst.hi = cvt(b)  [T12 recipe]
__device__ __forceinline__ uint32_t cvtpk(float a, float b) {
  uint32_t r;
  asm("v_cvt_pk_bf16_f32 %0, %1, %2" : "=v"(r) : "v"(a), "v"(b));
  return r;
}

// async global->LDS, 16B per lane, wave-uniform LDS base + lane*16
__device__ __forceinline__ void gload_lds16(const void* g, void* l) {
  __builtin_amdgcn_global_load_lds(
      (const __attribute__((address_space(1))) uint32_t*)(uintptr_t)g,
      (__attribute__((address_space(3))) uint32_t*)(uint32_t)(uintptr_t)l,
      16, 0, 0);
}

// ---------- f32 -> bf16 bulk convert ----------
__global__ __launch_bounds__(256)
void eagle3_cvt(const float* __restrict__ src, uint16_t* __restrict__ dst, int n8)
{
  int i = blockIdx.x * 256 + threadIdx.x;
  const int stride = gridDim.x * 256;
  for (; i < n8; i += stride) {
    const float4 a = ((const float4*)src)[i * 2];
    const float4 b = ((const float4*)src)[i * 2 + 1];
    ((bf8*)dst)[i] = cvt8(a, b);
  }
}

// ---------- triple f32 -> bf16 convert (Wk, Wv, Wo in one launch) ----------
__global__ __launch_bounds__(256)
void eagle3_cvt3(const float* __restrict__ s1, uint16_t* __restrict__ d1, int n1,
                 const float* __restrict__ s2, uint16_t* __restrict__ d2, int n2,
                 const float* __restrict__ s3, uint16_t* __restrict__ d3, int n3)
{
  int i = blockIdx.x * 256 + threadIdx.x;
  const int stride = gridDim.x * 256;
  const int tot = n1 + n2 + n3;
  for (; i < tot; i += stride) {
    const float* src; uint16_t* dst; int j;
    if (i < n1)           { src = s1; dst = d1; j = i; }
    else if (i < n1 + n2) { src = s2; dst = d2; j = i - n1; }
    else                  { src = s3; dst = d3; j = i - n1 - n2; }
    const float4 a = ((const float4*)src)[j * 2];
    const float4 b = ((const float4*)src)[j * 2 + 1];
    ((bf8*)dst)[j] = cvt8(a, b);
  }
}

// ---------- GEMM v7: KV projection, 128x128 tile, BK=32, 4-deep ring ----
// gemm3's proven ring discipline (4 slots, vmcnt(8/4/0) ladder, one barrier
// per K-step, stage t+3 -> slot (t-1)&3 after the barrier) shrunk to 128^2:
// LDS = 4 x (A 8KB + B 8KB) = 64KB -> 2 blocks/CU (16 waves/CU, 2x gemm5).
// 256 threads (4 waves 2x2), 4 gloads/thread/tile, both-sides (row>>1)&3
// chunk swizzle. Split epilogue: n0<1024 -> K with fused RoPE (128x128 bf16
// stash overlays ring slot A memory), else V plain.
__global__ __launch_bounds__(256, 2)
void eagle3_gemm7(const uint16_t* __restrict__ Ap, const uint16_t* __restrict__ Bp,
                  uint16_t* __restrict__ Kc, uint16_t* __restrict__ Vc,
                  const float* __restrict__ Cst, const float* __restrict__ Snt)
{
  __shared__ __align__(16) uint16_t As[4][128 * 32];   // 32 KB (also K stash)
  __shared__ __align__(16) uint16_t Bs[4][128 * 32];   // 32 KB
  const int K = 8192, lda = 8192, ldb = 8192;

  const int nwg = gridDim.x * gridDim.y;
  const int bid = blockIdx.y * gridDim.x + blockIdx.x;
  const int qq = nwg >> 3;
  const int sw = (bid & 7) * qq + (bid >> 3);
  const int bx = sw % gridDim.x, by = sw / gridDim.x;
  const int m0 = by * 128, n0 = bx * 128;

  const int tid = threadIdx.x, lane = tid & 63, w = tid >> 6;
  const int tl = lane & 15, g = lane >> 4;
  const int wr = (w >> 1) * 64, wc = (w & 1) * 64;

  f4 acc[4][4] = {};
  const int NT = K >> 5;

  // thread t stages chunks j = t (rows 0-63) and j = t+256 (rows 64-127) of
  // each 128x32 tile: row j>>2, slot j&3; source pre-swizzled by (row>>1)&3.
  const int r_  = tid >> 2;                       // 0..63
  const int cs_ = ((tid & 3) ^ ((r_ >> 1) & 3)) * 8;   // same for r_ and r_+64
  #define STAGE7(tt)                                                            \
    {                                                                           \
      const int kk = (tt) << 5;                                                 \
      const int bsel_ = (tt) & 3;                                               \
      gload_lds16(Ap + (size_t)(m0 + r_) * lda + kk + cs_,                      \
                  &As[bsel_][tid * 8]);                                         \
      gload_lds16(Ap + (size_t)(m0 + 64 + r_) * lda + kk + cs_,                 \
                  &As[bsel_][(tid + 256) * 8]);                                 \
      gload_lds16(Bp + (size_t)(n0 + r_) * ldb + kk + cs_,                      \
                  &Bs[bsel_][tid * 8]);                                         \
      gload_lds16(Bp + (size_t)(n0 + 64 + r_) * ldb + kk + cs_,                 \
                  &Bs[bsel_][(tid + 256) * 8]);                                 \
    }

  STAGE7(0);
  if (NT > 1) STAGE7(1);
  if (NT > 2) STAGE7(2);

  const int rc = (g ^ ((tl >> 1) & 3)) * 8;   // read-side XOR (rows ~ tl mod 16)

  for (int t = 0; t < NT; ++t) {
    if (t + 2 < NT)      asm volatile("s_waitcnt vmcnt(8)" ::: "memory");
    else if (t + 1 < NT) asm volatile("s_waitcnt vmcnt(4)" ::: "memory");
    else                 asm volatile("s_waitcnt vmcnt(0)" ::: "memory");
    __builtin_amdgcn_sched_barrier(0);
    __builtin_amdgcn_s_barrier();          // tile t visible; slot t-1 reads done
    __builtin_amdgcn_sched_barrier(0);

    if (t + 3 < NT) STAGE7(t + 3);         // -> slot (t+3)&3 == (t-1)&3, safe

    const int bsel = t & 3;
    bf8 af[4], bfr[4];
    #pragma unroll
    for (int i = 0; i < 4; ++i) {
      af[i]  = *(const bf8*)&As[bsel][(wr + i * 16 + tl) * 32 + rc];
      bfr[i] = *(const bf8*)&Bs[bsel][(wc + i * 16 + tl) * 32 + rc];
    }

    __builtin_amdgcn_s_setprio(1);
    #pragma unroll
    for (int mi = 0; mi < 4; ++mi)
      #pragma unroll
      for (int ni = 0; ni < 4; ++ni)
        acc[mi][ni] = __builtin_amdgcn_mfma_f32_16x16x32_bf16(af[mi], bfr[ni], acc[mi][ni], 0, 0, 0);
    __builtin_amdgcn_s_setprio(0);
  }
  #undef STAGE7

  const bool isK = (n0 < 1024);        // block-uniform
  const int c0 = n0 & 1023;
  if (isK) {
    // stash bf16 K tile into ring-slot A memory (all LDS reads done per-wave;
    // barrier orders the overwrite across waves)
    uint16_t* Kx = &As[0][0];          // 128*128 elems = 32 KB exactly
    __syncthreads();
    #pragma unroll
    for (int mi = 0; mi < 4; ++mi)
      #pragma unroll
      for (int r = 0; r < 4; ++r) {
        const int row = wr + mi * 16 + g * 4 + r;
        #pragma unroll
        for (int ni = 0; ni < 4; ++ni)
          Kx[row * 128 + wc + ni * 16 + tl] = f2bf(acc[mi][ni][r]);
      }
    __syncthreads();
    // rope: out_d = x_d*c -/+ x_{d^64}*s ; sign is wc-uniform
    #pragma unroll
    for (int mi = 0; mi < 4; ++mi)
      #pragma unroll
      for (int r = 0; r < 4; ++r) {
        const int row = wr + mi * 16 + g * 4 + r;
        const int s = (m0 + row) & 2047;
        #pragma unroll
        for (int ni = 0; ni < 4; ++ni) {
          const int d = wc + ni * 16 + tl;
          const float own = bf2f(Kx[row * 128 + d]);
          const float oth = bf2f(Kx[row * 128 + (d ^ 64)]);
          const float cv = Cst[s * 128 + d];
          const float sv = Snt[s * 128 + d];
          const float out = wc ? (own * cv + oth * sv) : (own * cv - oth * sv);
          Kc[(size_t)(m0 + row) * 1024 + c0 + d] = f2bf(out);
        }
      }
  } else {
    #pragma unroll
    for (int mi = 0; mi < 4; ++mi)
      #pragma unroll
      for (int r = 0; r < 4; ++r) {
        const int row = m0 + wr + mi * 16 + g * 4 + r;
        #pragma unroll
        for (int ni = 0; ni < 4; ++ni) {
          const int col = c0 + wc + ni * 16 + tl;
          Vc[(size_t)row * 1024 + col] = f2bf(acc[mi][ni][r]);
        }
      }
  }
}

// ---------- GEMM v5 (256x256, BK=64, 8-phase schedule) — unchanged ----------
template<bool OF32>
__global__ __launch_bounds__(512, 2)
void eagle3_gemm5(const uint16_t* __restrict__ Ap, const uint16_t* __restrict__ Bp,
                  void* __restrict__ Cp, int K, int lda, int ldb, int ldc)
{
  __shared__ __align__(16) uint16_t As[2][2][128 * 64];
  __shared__ __align__(16) uint16_t Bs[2][2][128 * 64];

  int bx, by;
  const int bid = blockIdx.y * gridDim.x + blockIdx.x;
  if (gridDim.x == 16 && gridDim.y == 16) {
    const int x = bid & 7, j = bid >> 3;
    by = (x >> 1) * 4 + (j >> 3);
    bx = (x & 1) * 8 + (j & 7);
  } else {
    const int nwg = gridDim.x * gridDim.y;
    const int qq = nwg >> 3;
    const int sw = (bid & 7) * qq + (bid >> 3);
    bx = sw % gridDim.x; by = sw / gridDim.x;
  }
  const int m0 = by * 256, n0 = bx * 256;

  const int tid = threadIdx.x, lane = tid & 63;
  const int tl = lane & 15, g = lane >> 4;
  const int w = tid >> 6;
  const int wm = w >> 2, wn = w & 3;
  const int bhf = wn >> 1;
  const int bl0 = (wn & 1) * 64;

  f4 acc[8][4] = {};
  const int NI = K >> 7;

  const int jr = tid >> 3;
  const int jc = ((tid & 7) ^ (jr & 7)) * 8;
  #define STG_A(slot, h, tt)                                                    \
    { const int kk_ = (tt) << 6;                                                \
      gload_lds16(Ap + (size_t)(m0 + (h)*128 + jr) * lda + kk_ + jc,            \
                  &As[slot][h][tid * 8]);                                       \
      gload_lds16(Ap + (size_t)(m0 + (h)*128 + 64 + jr) * lda + kk_ + jc,       \
                  &As[slot][h][(tid + 512) * 8]); }
  #define STG_B(slot, h, tt)                                                    \
    { const int kk_ = (tt) << 6;                                                \
      gload_lds16(Bp + (size_t)(n0 + (h)*128 + jr) * ldb + kk_ + jc,            \
                  &Bs[slot][h][tid * 8]);                                       \
      gload_lds16(Bp + (size_t)(n0 + (h)*128 + 64 + jr) * ldb + kk_ + jc,       \
                  &Bs[slot][h][(tid + 512) * 8]); }

  const int rk0 = ((0 + g) ^ (tl & 7)) * 8;
  const int rk1 = ((4 + g) ^ (tl & 7)) * 8;

  bf8 af[8], b0[4], b1[4];
  #define READ_A(slot, rh)                                                      \
    { _Pragma("unroll")                                                         \
      for (int m_ = 0; m_ < 4; ++m_) {                                          \
        const int R_ = (rh)*64 + m_*16 + tl;                                    \
        af[m_*2]   = *(const bf8*)&As[slot][wm][R_*64 + rk0];                   \
        af[m_*2+1] = *(const bf8*)&As[slot][wm][R_*64 + rk1];                   \
      } }
  #define READ_B(slot, ch, dst)                                                 \
    { _Pragma("unroll")                                                         \
      for (int c_ = 0; c_ < 2; ++c_) {                                          \
        const int R_ = bl0 + (ch)*32 + c_*16 + tl;                              \
        dst[c_*2]   = *(const bf8*)&Bs[slot][bhf][R_*64 + rk0];                 \
        dst[c_*2+1] = *(const bf8*)&Bs[slot][bhf][R_*64 + rk1];                 \
      } }
  #define MID_SYNC                                                              \
    __builtin_amdgcn_sched_barrier(0);                                          \
    __builtin_amdgcn_s_barrier();                                               \
    asm volatile("s_waitcnt lgkmcnt(0)" ::: "memory");                          \
    __builtin_amdgcn_sched_barrier(0);
  #define CLOSE_BAR                                                             \
    __builtin_amdgcn_sched_barrier(0);                                          \
    __builtin_amdgcn_s_barrier();                                               \
    __builtin_amdgcn_sched_barrier(0);
  #define MFMA16(rh, ch, bsrc)                                                  \
    { __builtin_amdgcn_s_setprio(1);                                            \
      _Pragma("unroll")                                                         \
      for (int m_ = 0; m_ < 4; ++m_) {                                          \
        _Pragma("unroll")                                                       \
        for (int c_ = 0; c_ < 2; ++c_) {                                        \
          acc[(rh)*4+m_][(ch)*2+c_] = __builtin_amdgcn_mfma_f32_16x16x32_bf16(  \
              af[m_*2],   bsrc[c_*2],   acc[(rh)*4+m_][(ch)*2+c_], 0, 0, 0);    \
          acc[(rh)*4+m_][(ch)*2+c_] = __builtin_amdgcn_mfma_f32_16x16x32_bf16(  \
              af[m_*2+1], bsrc[c_*2+1], acc[(rh)*4+m_][(ch)*2+c_], 0, 0, 0);    \
        } }                                                                     \
      __builtin_amdgcn_s_setprio(0); }

  STG_A(0, 0, 0); STG_A(0, 1, 0); STG_B(0, 0, 0); STG_B(0, 1, 0);
  STG_B(1, 0, 1); STG_B(1, 1, 1);
  asm volatile("s_waitcnt vmcnt(4)" ::: "memory");
  CLOSE_BAR;
  READ_B(0, 0, b0);

  for (int i = 0; i < NI; ++i) {
    const int T1 = 2 * i + 1;
    const bool more = (i + 1 < NI);

    READ_A(0, 0);
    STG_A(1, 0, T1);
    MID_SYNC; MFMA16(0, 0, b0); CLOSE_BAR;

    READ_B(0, 1, b1);
    STG_A(1, 1, T1);
    MID_SYNC; MFMA16(0, 1, b1); CLOSE_BAR;

    READ_A(0, 1);
    if (more) STG_B(0, 0, T1 + 1);
    MID_SYNC; MFMA16(1, 0, b0);
    if (more) { asm volatile("s_waitcnt vmcnt(6)" ::: "memory"); }
    else      { asm volatile("s_waitcnt vmcnt(4)" ::: "memory"); }
    CLOSE_BAR;

    READ_B(1, 0, b0);
    if (more) STG_B(0, 1, T1 + 1);
    MID_SYNC; MFMA16(1, 1, b1);
    if (more) { asm volatile("s_waitcnt vmcnt(4)" ::: "memory"); }
    else      { asm volatile("s_waitcnt vmcnt(0)" ::: "memory"); }
    CLOSE_BAR;

    READ_A(1, 0);
    if (more) STG_A(0, 0, T1 + 1);
    MID_SYNC; MFMA16(0, 0, b0); CLOSE_BAR;

    READ_B(1, 1, b1);
    if (more) STG_A(0, 1, T1 + 1);
    MID_SYNC; MFMA16(0, 1, b1); CLOSE_BAR;

    READ_A(1, 1);
    if (more) STG_B(1, 0, T1 + 2);
    MID_SYNC; MFMA16(1, 0, b0);
    if (more) { asm volatile("s_waitcnt vmcnt(6)" ::: "memory"); }
    CLOSE_BAR;

    if (more) { READ_B(0, 0, b0); STG_B(1, 1, T1 + 2); }
    MID_SYNC; MFMA16(1, 1, b1);
    if (more) { asm volatile("s_waitcnt vmcnt(4)" ::: "memory"); }
    CLOSE_BAR;
  }
  #undef STG_A
  #undef STG_B
  #undef READ_A
  #undef READ_B
  #undef MID_SYNC
  #undef CLOSE_BAR
  #undef MFMA16

  const int wr = wm * 128, wc = wn * 64;
  #pragma unroll
  for (int mi = 0; mi < 8; ++mi) {
    #pragma unroll
    for (int r = 0; r < 4; ++r) {
      const int row = m0 + wr + mi * 16 + g * 4 + r;
      #pragma unroll
      for (int ni = 0; ni < 4; ++ni) {
        const int col = n0 + wc + ni * 16 + tl;
        const float v = acc[mi][ni][r];
        if constexpr (OF32) ((float*)Cp)[(size_t)row * ldc + col] = v;
        else                ((uint16_t*)Cp)[(size_t)row * ldc + col] = f2bf(v);
      }
    }
  }
}

// ---------- V transpose: [b,t,h,d] -> [b,h,d,t] ----------
__global__ __launch_bounds__(256)
void eagle3_vtrans(const uint16_t* __restrict__ V, uint16_t* __restrict__ Vt)
{
  __shared__ uint16_t T[64 * 136];
  const int tid = threadIdx.x;
  const int t0 = blockIdx.x * 64;
  const int bh = blockIdx.y;
  const int b = bh >> 3, h = bh & 7;
  {
    const int r = tid >> 2, c0 = (tid & 3) * 32;
    const uint16_t* src = V + (size_t)(b * 2048 + t0 + r) * 1024 + h * 128 + c0;
    #pragma unroll
    for (int j = 0; j < 4; ++j)
      *(bf8*)&T[r * 136 + c0 + j * 8] = *(const bf8*)(src + j * 8);
  }
  __syncthreads();
  {
    const int d = tid >> 1, tc = (tid & 1) * 32;
    uint16_t* dst = Vt + ((size_t)bh * 128 + d) * 2048 + t0 + tc;
    #pragma unroll
    for (int cc = 0; cc < 4; ++cc) {
      bf8 v;
      #pragma unroll
      for (int j = 0; j < 8; ++j) v[j] = T[(tc + cc * 8 + j) * 136 + d];
      *(bf8*)&dst[cc * 8] = v;
    }
  }
}

// ---------- causal GQA flash attention v8 (v7 + T13 defer-max) ----------
__global__ __launch_bounds__(512, 4)
void eagle3_flash8(const uint16_t* __restrict__ Q, const uint16_t* __restrict__ Kt,
                   const uint16_t* __restrict__ Vt, uint16_t* __restrict__ O,
                   const float* __restrict__ Cst, const float* __restrict__ Snt)
{
  __shared__ __align__(16) uint16_t Ks[2][64 * 128];   // 32 KB
  __shared__ __align__(16) uint16_t Vs[2][128 * 64];   // 32 KB
  __shared__ __align__(16) uint16_t Pl[8][16 * 64];    // 16 KB (per-wave, swz)

  const int tid = threadIdx.x, lane = tid & 63, w = tid >> 6;
  const int tl = lane & 15, g = lane >> 4;

  const int bid = (int)blockIdx.x + ((int)blockIdx.y << 4) + ((int)blockIdx.z << 9);
  const int xcd = bid & 7, idx = bid >> 3;
  const int grp = xcd * 2 + (idx >> 6);
  const int j   = idx & 63;
  const int b = grp >> 3, hkv = grp & 7;
  const int hq = hkv * 4 + (j & 3);
  const int qt = 15 - (j >> 2);
  const int qrow0 = qt * 128 + w * 16;
  const int ntb = 2 * qt + 2;

  bf8 qf[4];
  {
    const int srow = qrow0 + tl;
    const uint16_t* qp = Q + ((size_t)(b * 2048 + srow)) * 4096 + hq * 128 + g * 8;
    #pragma unroll
    for (int kb = 0; kb < 4; ++kb) qf[kb] = *(const bf8*)(qp + kb * 32);
    const float* cp = Cst + (size_t)srow * 128 + g * 8;
    const float* sp = Snt + (size_t)srow * 128 + g * 8;
    #pragma unroll
    for (int kb = 0; kb < 2; ++kb) {
      const float4 c0 = *(const float4*)(cp + kb * 32);
      const float4 c1 = *(const float4*)(cp + kb * 32 + 4);
      const float4 s0 = *(const float4*)(sp + kb * 32);
      const float4 s1 = *(const float4*)(sp + kb * 32 + 4);
      const float cc[8] = {c0.x,c0.y,c0.z,c0.w,c1.x,c1.y,c1.z,c1.w};
      const float ss[8] = {s0.x,s0.y,s0.z,s0.w,s1.x,s1.y,s1.z,s1.w};
      #pragma unroll
      for (int e = 0; e < 8; ++e) {
        const float x1 = bf2f((uint16_t)qf[kb][e]);
        const float x2 = bf2f((uint16_t)qf[kb + 2][e]);
        qf[kb][e]     = (short)f2bf(x1 * cc[e] - x2 * ss[e]);
        qf[kb + 2][e] = (short)f2bf(x2 * cc[e] + x1 * ss[e]);
      }
    }
  }

  const uint16_t* Kbase = Kt + (size_t)b * 2048 * 1024 + hkv * 128;
  const uint16_t* Vtb   = Vt + ((size_t)(b * 8 + hkv) * 128) * 2048;

  bf8 onesf = {};
  if (tl == 0) {
    #pragma unroll
    for (int q8 = 0; q8 < 8; ++q8) onesf[q8] = (short)0x3F80;
  }

  f4 acc[8] = {};
  f4 accl = {};
  float rm[4] = {-3e38f, -3e38f, -3e38f, -3e38f};
  const float KS = 0.1275174f;                // log2(e)/sqrt(128)
  const float DEFER = 90.5f;                  // 8 nats in raw-score units

  #define STAGE_TILE(buf, t0s)                                                   \
    {                                                                            \
      _Pragma("unroll")                                                          \
      for (int i = 0; i < 2; ++i) {                                              \
        const int f = i * 512 + tid;                                             \
        const int r = f >> 4, c = f & 15;                                        \
        gload_lds16(Kbase + (size_t)((t0s) + r) * 1024 + ((c ^ (r & 7)) * 8),    \
                    &Ks[buf][(i * 512 + w * 64) * 8]);                           \
      }                                                                          \
      _Pragma("unroll")                                                          \
      for (int i = 0; i < 2; ++i) {                                              \
        const int f = i * 512 + tid;                                             \
        const int d = f >> 3, c = f & 7;                                         \
        gload_lds16(Vtb + (size_t)d * 2048 + (t0s) + ((c ^ (d & 7)) * 8),        \
                    &Vs[buf][(i * 512 + w * 64) * 8]);                           \
      }                                                                          \
    }

  STAGE_TILE(0, 0);

  for (int tb = 0; tb < ntb; ++tb) {
    const int cur = tb & 1;
    const int t0 = tb * 64;

    if (tb + 1 < ntb) {
      STAGE_TILE(cur ^ 1, t0 + 64);
      asm volatile("s_waitcnt vmcnt(4)" ::: "memory");
    } else {
      asm volatile("s_waitcnt vmcnt(0)" ::: "memory");
    }
    __builtin_amdgcn_sched_barrier(0);
    __builtin_amdgcn_s_barrier();

    const bool active = (t0 <= qrow0 + 15);
    if (active) {
      f4 s[4] = {};
      __builtin_amdgcn_s_setprio(1);
      #pragma unroll
      for (int cf = 0; cf < 4; ++cf) {
        #pragma unroll
        for (int kb = 0; kb < 4; ++kb) {
          const bf8 kf = *(const bf8*)&Ks[cur][(cf * 16 + tl) * 128 +
                                              (((kb * 4 + g) ^ (tl & 7)) * 8)];
          s[cf] = __builtin_amdgcn_mfma_f32_16x16x32_bf16(qf[kb], kf, s[cf], 0, 0, 0);
        }
      }
      __builtin_amdgcn_s_setprio(0);

      const bool edge = (t0 + 63 > qrow0);
      float p[4][4];
      #pragma unroll
      for (int r = 0; r < 4; ++r) {
        float v[4];
        #pragma unroll
        for (int cf = 0; cf < 4; ++cf) v[cf] = s[cf][r];
        if (edge) {
          const int qg = qrow0 + g * 4 + r;
          #pragma unroll
          for (int cf = 0; cf < 4; ++cf)
            if (t0 + cf * 16 + tl > qg) v[cf] = -3e38f;
        }
        float mx = fmaxf(fmaxf(v[0], v[1]), fmaxf(v[2], v[3]));
        mx = fmaxf(mx, __shfl_xor(mx, 1));
        mx = fmaxf(mx, __shfl_xor(mx, 2));
        mx = fmaxf(mx, __shfl_xor(mx, 4));
        mx = fmaxf(mx, __shfl_xor(mx, 8));
        if (mx > rm[r] + DEFER) {            // T13: rescale only on big growth
          const float corr = exp2f((rm[r] - mx) * KS);
          #pragma unroll
          for (int df = 0; df < 8; ++df) acc[df][r] *= corr;
          accl[r] *= corr;
          rm[r] = mx;
        }
        #pragma unroll
        for (int cf = 0; cf < 4; ++cf) p[r][cf] = exp2f((v[cf] - rm[r]) * KS);
      }

      #pragma unroll
      for (int r = 0; r < 4; ++r) {
        const uint32_t pk0 = cvtpk(p[r][0], p[r][1]);
        const uint32_t pk1 = cvtpk(p[r][2], p[r][3]);
        const int row = g * 4 + r;
        const int sw = row & 7;
        uint16_t* Pw = &Pl[w][row * 64 + (tl & 7)];
        Pw[(((tl >> 3) + 0) ^ sw) * 8] = (uint16_t)pk0;
        Pw[(((tl >> 3) + 2) ^ sw) * 8] = (uint16_t)(pk0 >> 16);
        Pw[(((tl >> 3) + 4) ^ sw) * 8] = (uint16_t)pk1;
        Pw[(((tl >> 3) + 6) ^ sw) * 8] = (uint16_t)(pk1 >> 16);
      }
      const bf8 pf0 = *(const bf8*)&Pl[w][tl * 64 + ((g ^ (tl & 7)) * 8)];
      const bf8 pf1 = *(const bf8*)&Pl[w][tl * 64 + (((4 + g) ^ (tl & 7)) * 8)];

      __builtin_amdgcn_s_setprio(1);
      accl = __builtin_amdgcn_mfma_f32_16x16x32_bf16(pf0, onesf, accl, 0, 0, 0);
      accl = __builtin_amdgcn_mfma_f32_16x16x32_bf16(pf1, onesf, accl, 0, 0, 0);
      #pragma unroll
      for (int df = 0; df < 8; ++df) {
        const int vrow = (df * 16 + tl) * 64;
        const bf8 v0 = *(const bf8*)&Vs[cur][vrow + ((g ^ (tl & 7)) * 8)];
        const bf8 v1 = *(const bf8*)&Vs[cur][vrow + (((4 + g) ^ (tl & 7)) * 8)];
        acc[df] = __builtin_amdgcn_mfma_f32_16x16x32_bf16(pf0, v0, acc[df], 0, 0, 0);
        acc[df] = __builtin_amdgcn_mfma_f32_16x16x32_bf16(pf1, v1, acc[df], 0, 0, 0);
      }
      __builtin_amdgcn_s_setprio(0);
    }

    __builtin_amdgcn_s_barrier();
  }
  #undef STAGE_TILE

  #pragma unroll
  for (int r = 0; r < 4; ++r) {
    const float l = __shfl(accl[r], lane & 48);
    const float inv = 1.0f / l;
    const size_t ob = ((size_t)(b * 2048 + qrow0 + g * 4 + r)) * 4096 + hq * 128 + tl;
    #pragma unroll
    for (int df = 0; df < 8; ++df)
      O[ob + df * 16] = f2bf(acc[df][r] * inv);
  }
}

// ---------- launch ----------
extern "C" void kernel_launch(void* const* d_in, const int* in_sizes, int n_in,
                              void* d_out, int out_size, void* d_ws, size_t ws_size,
                              hipStream_t stream) {
  const float* hs   = (const float*)d_in[0];
  const float* cosT = (const float*)d_in[2];
  const float* sinT = (const float*)d_in[3];
  const float* Wq   = (const float*)d_in[4];
  const float* Wk   = (const float*)d_in[5];
  const float* Wv   = (const float*)d_in[6];
  const float* Wo   = (const float*)d_in[7];

  // ---- workspace liveness (ws >= 112 MiB, proven rounds 8-15) ----
  char* ws = (char*)d_ws;
  uint16_t* qb   = (uint16_t*)(ws);                 // [  0M, 32M)
  uint16_t* kbuf = (uint16_t*)(ws + 33554432);      // [ 32M, 40M)
  uint16_t* vbuf = (uint16_t*)(ws + 41943040);      // [ 40M, 48M)
  uint16_t* wkv  = (uint16_t*)(ws + 50331648);      // [ 48M, 80M) (Wq first)
  uint16_t* vt   = (uint16_t*)(ws + 75497472);      // [ 72M, 80M)
  uint16_t* ctx  = (uint16_t*)(ws + 41943040);      // [ 40M, 72M)
  uint16_t* wobf = (uint16_t*)(ws + 83886080);      // [ 80M,112M)
  uint16_t* hsb  = (uint16_t*)d_out;

  const dim3 blk(256);

  // 1) hs f32 -> bf16 (once)
  eagle3_cvt<<<dim3(2048), blk, 0, stream>>>(hs, hsb, 4194304);

  // 2) Q projection (Wq bf16 at [48M,112M), dead after this gemm)
  eagle3_cvt<<<dim3(2048), blk, 0, stream>>>(Wq, wkv, 4194304);
  eagle3_gemm5<false><<<dim3(16, 16), dim3(512), 0, stream>>>(
      hsb, wkv, (void*)qb, 8192, 8192, 8192, 4096);

  // 3) remaining weights in ONE cvt: [Wk;Wv] -> [48M,80M), Wo -> [80M,112M)
  eagle3_cvt3<<<dim3(2048), blk, 0, stream>>>(
      Wk, wkv, 1048576, Wv, wkv + 8388608, 1048576, Wo, wobf, 2097152);

  // 4) fused K/V projection via 4-ring (+in-epilogue RoPE on K)
  eagle3_gemm7<<<dim3(16, 32), blk, 0, stream>>>(
      hsb, wkv, kbuf, vbuf, cosT, sinT);

  // 5) V transpose
  eagle3_vtrans<<<dim3(32, 16), blk, 0, stream>>>(vbuf, vt);

  // 6) causal GQA flash attention (in-register Q RoPE, defer-max) -> ctx
  eagle3_flash8<<<dim3(16, 32, 2), dim3(512), 0, stream>>>(
      qb, kbuf, vt, ctx, cosT, sinT);

  // 7) output projection: out = ctx * Wo^T (f32 out over dead hsb)
  eagle3_gemm5<true><<<dim3(16, 16), dim3(512), 0, stream>>>(
      ctx, wobf, d_out, 4096, 4096, 4096, 4096);
}

// Round 19
// 733.188 us; speedup vs baseline: 1.0231x; 1.0101x over previous
//
#include <hip/hip_runtime.h>
#include <stdint.h>

// ---------- common types / helpers ----------
typedef __attribute__((ext_vector_type(8))) short bf8;   // 8 x bf16 (4 VGPRs)
typedef __attribute__((ext_vector_type(4))) float f4;    // MFMA accumulator

__device__ __forceinline__ float bf2f(uint16_t u) {
  union { unsigned i; float f; } v; v.i = ((unsigned)u) << 16; return v.f;
}
__device__ __forceinline__ uint16_t f2bf(float f) {
  union { float f; unsigned i; } v; v.f = f;
  unsigned r = v.i + 0x7fffu + ((v.i >> 16) & 1u);   // RTNE
  return (uint16_t)(r >> 16);
}
__device__ __forceinline__ bf8 cvt8(float4 a, float4 b) {
  bf8 r;
  r[0]=(short)f2bf(a.x); r[1]=(short)f2bf(a.y); r[2]=(short)f2bf(a.z); r[3]=(short)f2bf(a.w);
  r[4]=(short)f2bf(b.x); r[5]=(short)f2bf(b.y); r[6]=(short)f2bf(b.z); r[7]=(short)f2bf(b.w);
  return r;
}
// packed f32x2 -> bf16x2 (RNE); dst.lo = cvt(a), dst.hi = cvt(b)  [T12 recipe]
__device__ __forceinline__ uint32_t cvtpk(float a, float b) {
  uint32_t r;
  asm("v_cvt_pk_bf16_f32 %0, %1, %2" : "=v"(r) : "v"(a), "v"(b));
  return r;
}

// async global->LDS, 16B per lane, wave-uniform LDS base + lane*16
__device__ __forceinline__ void gload_lds16(const void* g, void* l) {
  __builtin_amdgcn_global_load_lds(
      (const __attribute__((address_space(1))) uint32_t*)(uintptr_t)g,
      (__attribute__((address_space(3))) uint32_t*)(uint32_t)(uintptr_t)l,
      16, 0, 0);
}

// ---------- dual f32 -> bf16 convert (hs + Wq in one launch) ----------
__global__ __launch_bounds__(256)
void eagle3_cvt2(const float* __restrict__ s1, uint16_t* __restrict__ d1, int n1,
                 const float* __restrict__ s2, uint16_t* __restrict__ d2, int n2)
{
  int i = blockIdx.x * 256 + threadIdx.x;
  const int stride = gridDim.x * 256;
  const int tot = n1 + n2;
  for (; i < tot; i += stride) {
    const float* src; uint16_t* dst; int j;
    if (i < n1) { src = s1; dst = d1; j = i; }
    else        { src = s2; dst = d2; j = i - n1; }
    const float4 a = ((const float4*)src)[j * 2];
    const float4 b = ((const float4*)src)[j * 2 + 1];
    ((bf8*)dst)[j] = cvt8(a, b);
  }
}

// ---------- triple f32 -> bf16 convert (Wk, Wv, Wo in one launch) ----------
__global__ __launch_bounds__(256)
void eagle3_cvt3(const float* __restrict__ s1, uint16_t* __restrict__ d1, int n1,
                 const float* __restrict__ s2, uint16_t* __restrict__ d2, int n2,
                 const float* __restrict__ s3, uint16_t* __restrict__ d3, int n3)
{
  int i = blockIdx.x * 256 + threadIdx.x;
  const int stride = gridDim.x * 256;
  const int tot = n1 + n2 + n3;
  for (; i < tot; i += stride) {
    const float* src; uint16_t* dst; int j;
    if (i < n1)           { src = s1; dst = d1; j = i; }
    else if (i < n1 + n2) { src = s2; dst = d2; j = i - n1; }
    else                  { src = s3; dst = d3; j = i - n1 - n2; }
    const float4 a = ((const float4*)src)[j * 2];
    const float4 b = ((const float4*)src)[j * 2 + 1];
    ((bf8*)dst)[j] = cvt8(a, b);
  }
}

// ---------- GEMM v7: KV projection, 128x128 tile, BK=32, 4-deep ring ----
// 4 ring slots, vmcnt(8/4/0) ladder, one barrier per K-step; 64KB LDS ->
// 2 blocks/CU. Split epilogue: n0<1024 -> K with fused RoPE; n0>=1024 -> V
// written TRANSPOSED to vt[bh][d][t]. Both stashes use stride 128 (fit As
// exactly). NOTE (round-18 bug): vt must NOT alias the Wv weight region --
// gemm7 writes vt while other blocks still read B. Launch places vt in the
// old vbuf slot, disjoint from wkv.
__global__ __launch_bounds__(256, 2)
void eagle3_gemm7(const uint16_t* __restrict__ Ap, const uint16_t* __restrict__ Bp,
                  uint16_t* __restrict__ Kc, uint16_t* __restrict__ Vt,
                  const float* __restrict__ Cst, const float* __restrict__ Snt)
{
  __shared__ __align__(16) uint16_t As[4][128 * 32];   // 32 KB (also stash)
  __shared__ __align__(16) uint16_t Bs[4][128 * 32];   // 32 KB
  const int K = 8192, lda = 8192, ldb = 8192;

  const int nwg = gridDim.x * gridDim.y;
  const int bid = blockIdx.y * gridDim.x + blockIdx.x;
  const int qq = nwg >> 3;
  const int sw = (bid & 7) * qq + (bid >> 3);
  const int bx = sw % gridDim.x, by = sw / gridDim.x;
  const int m0 = by * 128, n0 = bx * 128;

  const int tid = threadIdx.x, lane = tid & 63, w = tid >> 6;
  const int tl = lane & 15, g = lane >> 4;
  const int wr = (w >> 1) * 64, wc = (w & 1) * 64;

  f4 acc[4][4] = {};
  const int NT = K >> 5;

  const int r_  = tid >> 2;                       // 0..63
  const int cs_ = ((tid & 3) ^ ((r_ >> 1) & 3)) * 8;
  #define STAGE7(tt)                                                            \
    {                                                                           \
      const int kk = (tt) << 5;                                                 \
      const int bsel_ = (tt) & 3;                                               \
      gload_lds16(Ap + (size_t)(m0 + r_) * lda + kk + cs_,                      \
                  &As[bsel_][tid * 8]);                                         \
      gload_lds16(Ap + (size_t)(m0 + 64 + r_) * lda + kk + cs_,                 \
                  &As[bsel_][(tid + 256) * 8]);                                 \
      gload_lds16(Bp + (size_t)(n0 + r_) * ldb + kk + cs_,                      \
                  &Bs[bsel_][tid * 8]);                                         \
      gload_lds16(Bp + (size_t)(n0 + 64 + r_) * ldb + kk + cs_,                 \
                  &Bs[bsel_][(tid + 256) * 8]);                                 \
    }

  STAGE7(0);
  if (NT > 1) STAGE7(1);
  if (NT > 2) STAGE7(2);

  const int rc = (g ^ ((tl >> 1) & 3)) * 8;

  for (int t = 0; t < NT; ++t) {
    if (t + 2 < NT)      asm volatile("s_waitcnt vmcnt(8)" ::: "memory");
    else if (t + 1 < NT) asm volatile("s_waitcnt vmcnt(4)" ::: "memory");
    else                 asm volatile("s_waitcnt vmcnt(0)" ::: "memory");
    __builtin_amdgcn_sched_barrier(0);
    __builtin_amdgcn_s_barrier();
    __builtin_amdgcn_sched_barrier(0);

    if (t + 3 < NT) STAGE7(t + 3);

    const int bsel = t & 3;
    bf8 af[4], bfr[4];
    #pragma unroll
    for (int i = 0; i < 4; ++i) {
      af[i]  = *(const bf8*)&As[bsel][(wr + i * 16 + tl) * 32 + rc];
      bfr[i] = *(const bf8*)&Bs[bsel][(wc + i * 16 + tl) * 32 + rc];
    }

    __builtin_amdgcn_s_setprio(1);
    #pragma unroll
    for (int mi = 0; mi < 4; ++mi)
      #pragma unroll
      for (int ni = 0; ni < 4; ++ni)
        acc[mi][ni] = __builtin_amdgcn_mfma_f32_16x16x32_bf16(af[mi], bfr[ni], acc[mi][ni], 0, 0, 0);
    __builtin_amdgcn_s_setprio(0);
  }
  #undef STAGE7

  const bool isK = (n0 < 1024);        // block-uniform
  const int c0 = n0 & 1023;
  if (isK) {
    // K: stash bf16 tile (stride 128, fits As exactly), then RoPE
    uint16_t* Kx = &As[0][0];          // 128*128 u16 = 32768 B == sizeof(As)
    __syncthreads();
    #pragma unroll
    for (int mi = 0; mi < 4; ++mi)
      #pragma unroll
      for (int r = 0; r < 4; ++r) {
        const int row = wr + mi * 16 + g * 4 + r;
        #pragma unroll
        for (int ni = 0; ni < 4; ++ni)
          Kx[row * 128 + wc + ni * 16 + tl] = f2bf(acc[mi][ni][r]);
      }
    __syncthreads();
    #pragma unroll
    for (int mi = 0; mi < 4; ++mi)
      #pragma unroll
      for (int r = 0; r < 4; ++r) {
        const int row = wr + mi * 16 + g * 4 + r;
        const int s = (m0 + row) & 2047;
        #pragma unroll
        for (int ni = 0; ni < 4; ++ni) {
          const int d = wc + ni * 16 + tl;
          const float own = bf2f(Kx[row * 128 + d]);
          const float oth = bf2f(Kx[row * 128 + (d ^ 64)]);
          const float cv = Cst[s * 128 + d];
          const float sv = Snt[s * 128 + d];
          const float out = wc ? (own * cv + oth * sv) : (own * cv - oth * sv);
          Kc[(size_t)(m0 + row) * 1024 + c0 + d] = f2bf(out);
        }
      }
  } else {
    // V: stash at stride 128, write transposed vt[bh][d][t] coalesced.
    uint16_t* Vx = &As[0][0];          // 128*128 u16 = 32768 B == sizeof(As)
    __syncthreads();
    #pragma unroll
    for (int mi = 0; mi < 4; ++mi)
      #pragma unroll
      for (int r = 0; r < 4; ++r) {
        const int row = wr + mi * 16 + g * 4 + r;   // local t
        #pragma unroll
        for (int ni = 0; ni < 4; ++ni)
          Vx[row * 128 + wc + ni * 16 + tl] = f2bf(acc[mi][ni][r]);
      }
    __syncthreads();
    const int b = m0 >> 11, h = c0 >> 7;
    const int d = tid >> 1, th = (tid & 1) * 64;
    uint16_t* dst = Vt + (((size_t)(b * 8 + h) * 128 + d) * 2048) + (m0 & 2047) + th;
    #pragma unroll
    for (int cc = 0; cc < 8; ++cc) {
      bf8 v;
      #pragma unroll
      for (int j = 0; j < 8; ++j) v[j] = Vx[(th + cc * 8 + j) * 128 + d];
      *(bf8*)&dst[cc * 8] = v;
    }
  }
}

// ---------- GEMM v5 (256x256, BK=64, 8-phase schedule) — unchanged ----------
template<bool OF32>
__global__ __launch_bounds__(512, 2)
void eagle3_gemm5(const uint16_t* __restrict__ Ap, const uint16_t* __restrict__ Bp,
                  void* __restrict__ Cp, int K, int lda, int ldb, int ldc)
{
  __shared__ __align__(16) uint16_t As[2][2][128 * 64];
  __shared__ __align__(16) uint16_t Bs[2][2][128 * 64];

  int bx, by;
  const int bid = blockIdx.y * gridDim.x + blockIdx.x;
  if (gridDim.x == 16 && gridDim.y == 16) {
    const int x = bid & 7, j = bid >> 3;
    by = (x >> 1) * 4 + (j >> 3);
    bx = (x & 1) * 8 + (j & 7);
  } else {
    const int nwg = gridDim.x * gridDim.y;
    const int qq = nwg >> 3;
    const int sw = (bid & 7) * qq + (bid >> 3);
    bx = sw % gridDim.x; by = sw / gridDim.x;
  }
  const int m0 = by * 256, n0 = bx * 256;

  const int tid = threadIdx.x, lane = tid & 63;
  const int tl = lane & 15, g = lane >> 4;
  const int w = tid >> 6;
  const int wm = w >> 2, wn = w & 3;
  const int bhf = wn >> 1;
  const int bl0 = (wn & 1) * 64;

  f4 acc[8][4] = {};
  const int NI = K >> 7;

  const int jr = tid >> 3;
  const int jc = ((tid & 7) ^ (jr & 7)) * 8;
  #define STG_A(slot, h, tt)                                                    \
    { const int kk_ = (tt) << 6;                                                \
      gload_lds16(Ap + (size_t)(m0 + (h)*128 + jr) * lda + kk_ + jc,            \
                  &As[slot][h][tid * 8]);                                       \
      gload_lds16(Ap + (size_t)(m0 + (h)*128 + 64 + jr) * lda + kk_ + jc,       \
                  &As[slot][h][(tid + 512) * 8]); }
  #define STG_B(slot, h, tt)                                                    \
    { const int kk_ = (tt) << 6;                                                \
      gload_lds16(Bp + (size_t)(n0 + (h)*128 + jr) * ldb + kk_ + jc,            \
                  &Bs[slot][h][tid * 8]);                                       \
      gload_lds16(Bp + (size_t)(n0 + (h)*128 + 64 + jr) * ldb + kk_ + jc,       \
                  &Bs[slot][h][(tid + 512) * 8]); }

  const int rk0 = ((0 + g) ^ (tl & 7)) * 8;
  const int rk1 = ((4 + g) ^ (tl & 7)) * 8;

  bf8 af[8], b0[4], b1[4];
  #define READ_A(slot, rh)                                                      \
    { _Pragma("unroll")                                                         \
      for (int m_ = 0; m_ < 4; ++m_) {                                          \
        const int R_ = (rh)*64 + m_*16 + tl;                                    \
        af[m_*2]   = *(const bf8*)&As[slot][wm][R_*64 + rk0];                   \
        af[m_*2+1] = *(const bf8*)&As[slot][wm][R_*64 + rk1];                   \
      } }
  #define READ_B(slot, ch, dst)                                                 \
    { _Pragma("unroll")                                                         \
      for (int c_ = 0; c_ < 2; ++c_) {                                          \
        const int R_ = bl0 + (ch)*32 + c_*16 + tl;                              \
        dst[c_*2]   = *(const bf8*)&Bs[slot][bhf][R_*64 + rk0];                 \
        dst[c_*2+1] = *(const bf8*)&Bs[slot][bhf][R_*64 + rk1];                 \
      } }
  #define MID_SYNC                                                              \
    __builtin_amdgcn_sched_barrier(0);                                          \
    __builtin_amdgcn_s_barrier();                                               \
    asm volatile("s_waitcnt lgkmcnt(0)" ::: "memory");                          \
    __builtin_amdgcn_sched_barrier(0);
  #define CLOSE_BAR                                                             \
    __builtin_amdgcn_sched_barrier(0);                                          \
    __builtin_amdgcn_s_barrier();                                               \
    __builtin_amdgcn_sched_barrier(0);
  #define MFMA16(rh, ch, bsrc)                                                  \
    { __builtin_amdgcn_s_setprio(1);                                            \
      _Pragma("unroll")                                                         \
      for (int m_ = 0; m_ < 4; ++m_) {                                          \
        _Pragma("unroll")                                                       \
        for (int c_ = 0; c_ < 2; ++c_) {                                        \
          acc[(rh)*4+m_][(ch)*2+c_] = __builtin_amdgcn_mfma_f32_16x16x32_bf16(  \
              af[m_*2],   bsrc[c_*2],   acc[(rh)*4+m_][(ch)*2+c_], 0, 0, 0);    \
          acc[(rh)*4+m_][(ch)*2+c_] = __builtin_amdgcn_mfma_f32_16x16x32_bf16(  \
              af[m_*2+1], bsrc[c_*2+1], acc[(rh)*4+m_][(ch)*2+c_], 0, 0, 0);    \
        } }                                                                     \
      __builtin_amdgcn_s_setprio(0); }

  STG_A(0, 0, 0); STG_A(0, 1, 0); STG_B(0, 0, 0); STG_B(0, 1, 0);
  STG_B(1, 0, 1); STG_B(1, 1, 1);
  asm volatile("s_waitcnt vmcnt(4)" ::: "memory");
  CLOSE_BAR;
  READ_B(0, 0, b0);

  for (int i = 0; i < NI; ++i) {
    const int T1 = 2 * i + 1;
    const bool more = (i + 1 < NI);

    READ_A(0, 0);
    STG_A(1, 0, T1);
    MID_SYNC; MFMA16(0, 0, b0); CLOSE_BAR;

    READ_B(0, 1, b1);
    STG_A(1, 1, T1);
    MID_SYNC; MFMA16(0, 1, b1); CLOSE_BAR;

    READ_A(0, 1);
    if (more) STG_B(0, 0, T1 + 1);
    MID_SYNC; MFMA16(1, 0, b0);
    if (more) { asm volatile("s_waitcnt vmcnt(6)" ::: "memory"); }
    else      { asm volatile("s_waitcnt vmcnt(4)" ::: "memory"); }
    CLOSE_BAR;

    READ_B(1, 0, b0);
    if (more) STG_B(0, 1, T1 + 1);
    MID_SYNC; MFMA16(1, 1, b1);
    if (more) { asm volatile("s_waitcnt vmcnt(4)" ::: "memory"); }
    else      { asm volatile("s_waitcnt vmcnt(0)" ::: "memory"); }
    CLOSE_BAR;

    READ_A(1, 0);
    if (more) STG_A(0, 0, T1 + 1);
    MID_SYNC; MFMA16(0, 0, b0); CLOSE_BAR;

    READ_B(1, 1, b1);
    if (more) STG_A(0, 1, T1 + 1);
    MID_SYNC; MFMA16(0, 1, b1); CLOSE_BAR;

    READ_A(1, 1);
    if (more) STG_B(1, 0, T1 + 2);
    MID_SYNC; MFMA16(1, 0, b0);
    if (more) { asm volatile("s_waitcnt vmcnt(6)" ::: "memory"); }
    CLOSE_BAR;

    if (more) { READ_B(0, 0, b0); STG_B(1, 1, T1 + 2); }
    MID_SYNC; MFMA16(1, 1, b1);
    if (more) { asm volatile("s_waitcnt vmcnt(4)" ::: "memory"); }
    CLOSE_BAR;
  }
  #undef STG_A
  #undef STG_B
  #undef READ_A
  #undef READ_B
  #undef MID_SYNC
  #undef CLOSE_BAR
  #undef MFMA16

  const int wr = wm * 128, wc = wn * 64;
  #pragma unroll
  for (int mi = 0; mi < 8; ++mi) {
    #pragma unroll
    for (int r = 0; r < 4; ++r) {
      const int row = m0 + wr + mi * 16 + g * 4 + r;
      #pragma unroll
      for (int ni = 0; ni < 4; ++ni) {
        const int col = n0 + wc + ni * 16 + tl;
        const float v = acc[mi][ni][r];
        if constexpr (OF32) ((float*)Cp)[(size_t)row * ldc + col] = v;
        else                ((uint16_t*)Cp)[(size_t)row * ldc + col] = f2bf(v);
      }
    }
  }
}

// ---------- causal GQA flash attention v8 (unchanged) ----------
__global__ __launch_bounds__(512, 4)
void eagle3_flash8(const uint16_t* __restrict__ Q, const uint16_t* __restrict__ Kt,
                   const uint16_t* __restrict__ Vt, uint16_t* __restrict__ O,
                   const float* __restrict__ Cst, const float* __restrict__ Snt)
{
  __shared__ __align__(16) uint16_t Ks[2][64 * 128];   // 32 KB
  __shared__ __align__(16) uint16_t Vs[2][128 * 64];   // 32 KB
  __shared__ __align__(16) uint16_t Pl[8][16 * 64];    // 16 KB (per-wave, swz)

  const int tid = threadIdx.x, lane = tid & 63, w = tid >> 6;
  const int tl = lane & 15, g = lane >> 4;

  const int bid = (int)blockIdx.x + ((int)blockIdx.y << 4) + ((int)blockIdx.z << 9);
  const int xcd = bid & 7, idx = bid >> 3;
  const int grp = xcd * 2 + (idx >> 6);
  const int j   = idx & 63;
  const int b = grp >> 3, hkv = grp & 7;
  const int hq = hkv * 4 + (j & 3);
  const int qt = 15 - (j >> 2);
  const int qrow0 = qt * 128 + w * 16;
  const int ntb = 2 * qt + 2;

  bf8 qf[4];
  {
    const int srow = qrow0 + tl;
    const uint16_t* qp = Q + ((size_t)(b * 2048 + srow)) * 4096 + hq * 128 + g * 8;
    #pragma unroll
    for (int kb = 0; kb < 4; ++kb) qf[kb] = *(const bf8*)(qp + kb * 32);
    const float* cp = Cst + (size_t)srow * 128 + g * 8;
    const float* sp = Snt + (size_t)srow * 128 + g * 8;
    #pragma unroll
    for (int kb = 0; kb < 2; ++kb) {
      const float4 c0 = *(const float4*)(cp + kb * 32);
      const float4 c1 = *(const float4*)(cp + kb * 32 + 4);
      const float4 s0 = *(const float4*)(sp + kb * 32);
      const float4 s1 = *(const float4*)(sp + kb * 32 + 4);
      const float cc[8] = {c0.x,c0.y,c0.z,c0.w,c1.x,c1.y,c1.z,c1.w};
      const float ss[8] = {s0.x,s0.y,s0.z,s0.w,s1.x,s1.y,s1.z,s1.w};
      #pragma unroll
      for (int e = 0; e < 8; ++e) {
        const float x1 = bf2f((uint16_t)qf[kb][e]);
        const float x2 = bf2f((uint16_t)qf[kb + 2][e]);
        qf[kb][e]     = (short)f2bf(x1 * cc[e] - x2 * ss[e]);
        qf[kb + 2][e] = (short)f2bf(x2 * cc[e] + x1 * ss[e]);
      }
    }
  }

  const uint16_t* Kbase = Kt + (size_t)b * 2048 * 1024 + hkv * 128;
  const uint16_t* Vtb   = Vt + ((size_t)(b * 8 + hkv) * 128) * 2048;

  bf8 onesf = {};
  if (tl == 0) {
    #pragma unroll
    for (int q8 = 0; q8 < 8; ++q8) onesf[q8] = (short)0x3F80;
  }

  f4 acc[8] = {};
  f4 accl = {};
  float rm[4] = {-3e38f, -3e38f, -3e38f, -3e38f};
  const float KS = 0.1275174f;                // log2(e)/sqrt(128)
  const float DEFER = 90.5f;                  // 8 nats in raw-score units

  #define STAGE_TILE(buf, t0s)                                                   \
    {                                                                            \
      _Pragma("unroll")                                                          \
      for (int i = 0; i < 2; ++i) {                                              \
        const int f = i * 512 + tid;                                             \
        const int r = f >> 4, c = f & 15;                                        \
        gload_lds16(Kbase + (size_t)((t0s) + r) * 1024 + ((c ^ (r & 7)) * 8),    \
                    &Ks[buf][(i * 512 + w * 64) * 8]);                           \
      }                                                                          \
      _Pragma("unroll")                                                          \
      for (int i = 0; i < 2; ++i) {                                              \
        const int f = i * 512 + tid;                                             \
        const int d = f >> 3, c = f & 7;                                         \
        gload_lds16(Vtb + (size_t)d * 2048 + (t0s) + ((c ^ (d & 7)) * 8),        \
                    &Vs[buf][(i * 512 + w * 64) * 8]);                           \
      }                                                                          \
    }

  STAGE_TILE(0, 0);

  for (int tb = 0; tb < ntb; ++tb) {
    const int cur = tb & 1;
    const int t0 = tb * 64;

    if (tb + 1 < ntb) {
      STAGE_TILE(cur ^ 1, t0 + 64);
      asm volatile("s_waitcnt vmcnt(4)" ::: "memory");
    } else {
      asm volatile("s_waitcnt vmcnt(0)" ::: "memory");
    }
    __builtin_amdgcn_sched_barrier(0);
    __builtin_amdgcn_s_barrier();

    const bool active = (t0 <= qrow0 + 15);
    if (active) {
      f4 s[4] = {};
      __builtin_amdgcn_s_setprio(1);
      #pragma unroll
      for (int cf = 0; cf < 4; ++cf) {
        #pragma unroll
        for (int kb = 0; kb < 4; ++kb) {
          const bf8 kf = *(const bf8*)&Ks[cur][(cf * 16 + tl) * 128 +
                                              (((kb * 4 + g) ^ (tl & 7)) * 8)];
          s[cf] = __builtin_amdgcn_mfma_f32_16x16x32_bf16(qf[kb], kf, s[cf], 0, 0, 0);
        }
      }
      __builtin_amdgcn_s_setprio(0);

      const bool edge = (t0 + 63 > qrow0);
      float p[4][4];
      #pragma unroll
      for (int r = 0; r < 4; ++r) {
        float v[4];
        #pragma unroll
        for (int cf = 0; cf < 4; ++cf) v[cf] = s[cf][r];
        if (edge) {
          const int qg = qrow0 + g * 4 + r;
          #pragma unroll
          for (int cf = 0; cf < 4; ++cf)
            if (t0 + cf * 16 + tl > qg) v[cf] = -3e38f;
        }
        float mx = fmaxf(fmaxf(v[0], v[1]), fmaxf(v[2], v[3]));
        mx = fmaxf(mx, __shfl_xor(mx, 1));
        mx = fmaxf(mx, __shfl_xor(mx, 2));
        mx = fmaxf(mx, __shfl_xor(mx, 4));
        mx = fmaxf(mx, __shfl_xor(mx, 8));
        if (mx > rm[r] + DEFER) {
          const float corr = exp2f((rm[r] - mx) * KS);
          #pragma unroll
          for (int df = 0; df < 8; ++df) acc[df][r] *= corr;
          accl[r] *= corr;
          rm[r] = mx;
        }
        #pragma unroll
        for (int cf = 0; cf < 4; ++cf) p[r][cf] = exp2f((v[cf] - rm[r]) * KS);
      }

      #pragma unroll
      for (int r = 0; r < 4; ++r) {
        const uint32_t pk0 = cvtpk(p[r][0], p[r][1]);
        const uint32_t pk1 = cvtpk(p[r][2], p[r][3]);
        const int row = g * 4 + r;
        const int sw = row & 7;
        uint16_t* Pw = &Pl[w][row * 64 + (tl & 7)];
        Pw[(((tl >> 3) + 0) ^ sw) * 8] = (uint16_t)pk0;
        Pw[(((tl >> 3) + 2) ^ sw) * 8] = (uint16_t)(pk0 >> 16);
        Pw[(((tl >> 3) + 4) ^ sw) * 8] = (uint16_t)pk1;
        Pw[(((tl >> 3) + 6) ^ sw) * 8] = (uint16_t)(pk1 >> 16);
      }
      const bf8 pf0 = *(const bf8*)&Pl[w][tl * 64 + ((g ^ (tl & 7)) * 8)];
      const bf8 pf1 = *(const bf8*)&Pl[w][tl * 64 + (((4 + g) ^ (tl & 7)) * 8)];

      __builtin_amdgcn_s_setprio(1);
      accl = __builtin_amdgcn_mfma_f32_16x16x32_bf16(pf0, onesf, accl, 0, 0, 0);
      accl = __builtin_amdgcn_mfma_f32_16x16x32_bf16(pf1, onesf, accl, 0, 0, 0);
      #pragma unroll
      for (int df = 0; df < 8; ++df) {
        const int vrow = (df * 16 + tl) * 64;
        const bf8 v0 = *(const bf8*)&Vs[cur][vrow + ((g ^ (tl & 7)) * 8)];
        const bf8 v1 = *(const bf8*)&Vs[cur][vrow + (((4 + g) ^ (tl & 7)) * 8)];
        acc[df] = __builtin_amdgcn_mfma_f32_16x16x32_bf16(pf0, v0, acc[df], 0, 0, 0);
        acc[df] = __builtin_amdgcn_mfma_f32_16x16x32_bf16(pf1, v1, acc[df], 0, 0, 0);
      }
      __builtin_amdgcn_s_setprio(0);
    }

    __builtin_amdgcn_s_barrier();
  }
  #undef STAGE_TILE

  #pragma unroll
  for (int r = 0; r < 4; ++r) {
    const float l = __shfl(accl[r], lane & 48);
    const float inv = 1.0f / l;
    const size_t ob = ((size_t)(b * 2048 + qrow0 + g * 4 + r)) * 4096 + hq * 128 + tl;
    #pragma unroll
    for (int df = 0; df < 8; ++df)
      O[ob + df * 16] = f2bf(acc[df][r] * inv);
  }
}

// ---------- launch ----------
extern "C" void kernel_launch(void* const* d_in, const int* in_sizes, int n_in,
                              void* d_out, int out_size, void* d_ws, size_t ws_size,
                              hipStream_t stream) {
  const float* hs   = (const float*)d_in[0];
  const float* cosT = (const float*)d_in[2];
  const float* sinT = (const float*)d_in[3];
  const float* Wq   = (const float*)d_in[4];
  const float* Wk   = (const float*)d_in[5];
  const float* Wv   = (const float*)d_in[6];
  const float* Wo   = (const float*)d_in[7];

  // ---- workspace liveness (ws >= 112 MiB, proven rounds 8-16) ----
  // hsb = d_out [4096,8192] bf16 (64MB)   live: cvt2 -> KV gemm
  // [  0M, 32M) qb    live: Q gemm -> flash
  // [ 32M, 40M) kbuf  live: KV gemm (rope fused) -> flash
  // [ 40M, 48M) vt    live: KV gemm (V-transpose epilogue) -> flash
  //                   (DISJOINT from wkv -- round-17/18 bug had vt aliasing
  //                    the Wv weight tail that gemm7 was still reading)
  // [ 48M, 80M) wkv   Wq bf16 first (dead after Q gemm), then [Wk;Wv]
  //                   (dead after KV gemm)
  // [ 48M, 80M) ctx   live: flash -> Wo gemm (over dead wkv)
  // [ 80M,112M) wobf  live: cvt3 -> Wo gemm
  char* ws = (char*)d_ws;
  uint16_t* qb   = (uint16_t*)(ws);
  uint16_t* kbuf = (uint16_t*)(ws + 33554432);
  uint16_t* vt   = (uint16_t*)(ws + 41943040);
  uint16_t* wkv  = (uint16_t*)(ws + 50331648);
  uint16_t* ctx  = (uint16_t*)(ws + 50331648);
  uint16_t* wobf = (uint16_t*)(ws + 83886080);
  uint16_t* hsb  = (uint16_t*)d_out;

  const dim3 blk(256);

  // 1) hs + Wq f32 -> bf16 in one launch
  eagle3_cvt2<<<dim3(2048), blk, 0, stream>>>(hs, hsb, 4194304, Wq, wkv, 4194304);

  // 2) Q projection (Wq bf16 at [48M,112M), dead after this gemm)
  eagle3_gemm5<false><<<dim3(16, 16), dim3(512), 0, stream>>>(
      hsb, wkv, (void*)qb, 8192, 8192, 8192, 4096);

  // 3) remaining weights in ONE cvt: [Wk;Wv] -> [48M,80M), Wo -> [80M,112M)
  eagle3_cvt3<<<dim3(2048), blk, 0, stream>>>(
      Wk, wkv, 1048576, Wv, wkv + 8388608, 1048576, Wo, wobf, 2097152);

  // 4) fused K/V projection via 4-ring; K gets RoPE, V written transposed
  //    into vt at [40M,48M) (disjoint from the wkv weights being read)
  eagle3_gemm7<<<dim3(16, 32), blk, 0, stream>>>(
      hsb, wkv, kbuf, vt, cosT, sinT);

  // 5) causal GQA flash attention (in-register Q RoPE, defer-max) -> ctx
  eagle3_flash8<<<dim3(16, 32, 2), dim3(512), 0, stream>>>(
      qb, kbuf, vt, ctx, cosT, sinT);

  // 6) output projection: out = ctx * Wo^T (f32 out over dead hsb)
  eagle3_gemm5<true><<<dim3(16, 16), dim3(512), 0, stream>>>(
      ctx, wobf, d_out, 4096, 4096, 4096, 4096);
}

// Round 20
// 732.801 us; speedup vs baseline: 1.0237x; 1.0005x over previous
//
#include <hip/hip_runtime.h>
#include <stdint.h>

// ---------- common types / helpers ----------
typedef __attribute__((ext_vector_type(8))) short bf8;   // 8 x bf16 (4 VGPRs)
typedef __attribute__((ext_vector_type(4))) float f4;    // MFMA accumulator

__device__ __forceinline__ float bf2f(uint16_t u) {
  union { unsigned i; float f; } v; v.i = ((unsigned)u) << 16; return v.f;
}
__device__ __forceinline__ uint16_t f2bf(float f) {
  union { float f; unsigned i; } v; v.f = f;
  unsigned r = v.i + 0x7fffu + ((v.i >> 16) & 1u);   // RTNE
  return (uint16_t)(r >> 16);
}
// packed f32x2 -> bf16x2 (RNE); dst.lo = cvt(a), dst.hi = cvt(b)  [T12 recipe]
__device__ __forceinline__ uint32_t cvtpk(float a, float b) {
  uint32_t r;
  asm("v_cvt_pk_bf16_f32 %0, %1, %2" : "=v"(r) : "v"(a), "v"(b));
  return r;
}
// 8 x f32 -> 8 x bf16 via 4 cvt_pk (RNE, same rounding as f2bf; no NaNs here)
__device__ __forceinline__ bf8 cvt8(float4 a, float4 b) {
  union { uint32_t u[4]; bf8 v; } r;
  r.u[0] = cvtpk(a.x, a.y);
  r.u[1] = cvtpk(a.z, a.w);
  r.u[2] = cvtpk(b.x, b.y);
  r.u[3] = cvtpk(b.z, b.w);
  return r.v;
}

// async global->LDS, 16B per lane, wave-uniform LDS base + lane*16
__device__ __forceinline__ void gload_lds16(const void* g, void* l) {
  __builtin_amdgcn_global_load_lds(
      (const __attribute__((address_space(1))) uint32_t*)(uintptr_t)g,
      (__attribute__((address_space(3))) uint32_t*)(uint32_t)(uintptr_t)l,
      16, 0, 0);
}

// ---------- dual f32 -> bf16 convert (hs + Wq in one launch) ----------
__global__ __launch_bounds__(256)
void eagle3_cvt2(const float* __restrict__ s1, uint16_t* __restrict__ d1, int n1,
                 const float* __restrict__ s2, uint16_t* __restrict__ d2, int n2)
{
  int i = blockIdx.x * 256 + threadIdx.x;
  const int stride = gridDim.x * 256;
  const int tot = n1 + n2;
  for (; i < tot; i += stride) {
    const float* src; uint16_t* dst; int j;
    if (i < n1) { src = s1; dst = d1; j = i; }
    else        { src = s2; dst = d2; j = i - n1; }
    const float4 a = ((const float4*)src)[j * 2];
    const float4 b = ((const float4*)src)[j * 2 + 1];
    ((bf8*)dst)[j] = cvt8(a, b);
  }
}

// ---------- triple f32 -> bf16 convert (Wk, Wv, Wo in one launch) ----------
__global__ __launch_bounds__(256)
void eagle3_cvt3(const float* __restrict__ s1, uint16_t* __restrict__ d1, int n1,
                 const float* __restrict__ s2, uint16_t* __restrict__ d2, int n2,
                 const float* __restrict__ s3, uint16_t* __restrict__ d3, int n3)
{
  int i = blockIdx.x * 256 + threadIdx.x;
  const int stride = gridDim.x * 256;
  const int tot = n1 + n2 + n3;
  for (; i < tot; i += stride) {
    const float* src; uint16_t* dst; int j;
    if (i < n1)           { src = s1; dst = d1; j = i; }
    else if (i < n1 + n2) { src = s2; dst = d2; j = i - n1; }
    else                  { src = s3; dst = d3; j = i - n1 - n2; }
    const float4 a = ((const float4*)src)[j * 2];
    const float4 b = ((const float4*)src)[j * 2 + 1];
    ((bf8*)dst)[j] = cvt8(a, b);
  }
}

// ---------- GEMM v7: KV projection, 128x128 tile, BK=32, 4-deep ring ----
// 4 ring slots, vmcnt(8/4/0) ladder, one barrier per K-step; 64KB LDS ->
// 2 blocks/CU. Split epilogue: n0<1024 -> K with fused RoPE; n0>=1024 -> V
// written TRANSPOSED to vt[bh][d][t]. Both stashes use stride 128 (fit As
// exactly). vt must NOT alias the Wv weight region (round-18 lesson).
__global__ __launch_bounds__(256, 2)
void eagle3_gemm7(const uint16_t* __restrict__ Ap, const uint16_t* __restrict__ Bp,
                  uint16_t* __restrict__ Kc, uint16_t* __restrict__ Vt,
                  const float* __restrict__ Cst, const float* __restrict__ Snt)
{
  __shared__ __align__(16) uint16_t As[4][128 * 32];   // 32 KB (also stash)
  __shared__ __align__(16) uint16_t Bs[4][128 * 32];   // 32 KB
  const int K = 8192, lda = 8192, ldb = 8192;

  const int nwg = gridDim.x * gridDim.y;
  const int bid = blockIdx.y * gridDim.x + blockIdx.x;
  const int qq = nwg >> 3;
  const int sw = (bid & 7) * qq + (bid >> 3);
  const int bx = sw % gridDim.x, by = sw / gridDim.x;
  const int m0 = by * 128, n0 = bx * 128;

  const int tid = threadIdx.x, lane = tid & 63, w = tid >> 6;
  const int tl = lane & 15, g = lane >> 4;
  const int wr = (w >> 1) * 64, wc = (w & 1) * 64;

  f4 acc[4][4] = {};
  const int NT = K >> 5;

  const int r_  = tid >> 2;                       // 0..63
  const int cs_ = ((tid & 3) ^ ((r_ >> 1) & 3)) * 8;
  #define STAGE7(tt)                                                            \
    {                                                                           \
      const int kk = (tt) << 5;                                                 \
      const int bsel_ = (tt) & 3;                                               \
      gload_lds16(Ap + (size_t)(m0 + r_) * lda + kk + cs_,                      \
                  &As[bsel_][tid * 8]);                                         \
      gload_lds16(Ap + (size_t)(m0 + 64 + r_) * lda + kk + cs_,                 \
                  &As[bsel_][(tid + 256) * 8]);                                 \
      gload_lds16(Bp + (size_t)(n0 + r_) * ldb + kk + cs_,                      \
                  &Bs[bsel_][tid * 8]);                                         \
      gload_lds16(Bp + (size_t)(n0 + 64 + r_) * ldb + kk + cs_,                 \
                  &Bs[bsel_][(tid + 256) * 8]);                                 \
    }

  STAGE7(0);
  if (NT > 1) STAGE7(1);
  if (NT > 2) STAGE7(2);

  const int rc = (g ^ ((tl >> 1) & 3)) * 8;

  for (int t = 0; t < NT; ++t) {
    if (t + 2 < NT)      asm volatile("s_waitcnt vmcnt(8)" ::: "memory");
    else if (t + 1 < NT) asm volatile("s_waitcnt vmcnt(4)" ::: "memory");
    else                 asm volatile("s_waitcnt vmcnt(0)" ::: "memory");
    __builtin_amdgcn_sched_barrier(0);
    __builtin_amdgcn_s_barrier();
    __builtin_amdgcn_sched_barrier(0);

    if (t + 3 < NT) STAGE7(t + 3);

    const int bsel = t & 3;
    bf8 af[4], bfr[4];
    #pragma unroll
    for (int i = 0; i < 4; ++i) {
      af[i]  = *(const bf8*)&As[bsel][(wr + i * 16 + tl) * 32 + rc];
      bfr[i] = *(const bf8*)&Bs[bsel][(wc + i * 16 + tl) * 32 + rc];
    }

    __builtin_amdgcn_s_setprio(1);
    #pragma unroll
    for (int mi = 0; mi < 4; ++mi)
      #pragma unroll
      for (int ni = 0; ni < 4; ++ni)
        acc[mi][ni] = __builtin_amdgcn_mfma_f32_16x16x32_bf16(af[mi], bfr[ni], acc[mi][ni], 0, 0, 0);
    __builtin_amdgcn_s_setprio(0);
  }
  #undef STAGE7

  const bool isK = (n0 < 1024);        // block-uniform
  const int c0 = n0 & 1023;
  if (isK) {
    // K: stash bf16 tile (stride 128, fits As exactly), then RoPE
    uint16_t* Kx = &As[0][0];          // 128*128 u16 = 32768 B == sizeof(As)
    __syncthreads();
    #pragma unroll
    for (int mi = 0; mi < 4; ++mi)
      #pragma unroll
      for (int r = 0; r < 4; ++r) {
        const int row = wr + mi * 16 + g * 4 + r;
        #pragma unroll
        for (int ni = 0; ni < 4; ++ni)
          Kx[row * 128 + wc + ni * 16 + tl] = f2bf(acc[mi][ni][r]);
      }
    __syncthreads();
    #pragma unroll
    for (int mi = 0; mi < 4; ++mi)
      #pragma unroll
      for (int r = 0; r < 4; ++r) {
        const int row = wr + mi * 16 + g * 4 + r;
        const int s = (m0 + row) & 2047;
        #pragma unroll
        for (int ni = 0; ni < 4; ++ni) {
          const int d = wc + ni * 16 + tl;
          const float own = bf2f(Kx[row * 128 + d]);
          const float oth = bf2f(Kx[row * 128 + (d ^ 64)]);
          const float cv = Cst[s * 128 + d];
          const float sv = Snt[s * 128 + d];
          const float out = wc ? (own * cv + oth * sv) : (own * cv - oth * sv);
          Kc[(size_t)(m0 + row) * 1024 + c0 + d] = f2bf(out);
        }
      }
  } else {
    // V: stash at stride 128, write transposed vt[bh][d][t] coalesced.
    uint16_t* Vx = &As[0][0];          // 128*128 u16 = 32768 B == sizeof(As)
    __syncthreads();
    #pragma unroll
    for (int mi = 0; mi < 4; ++mi)
      #pragma unroll
      for (int r = 0; r < 4; ++r) {
        const int row = wr + mi * 16 + g * 4 + r;   // local t
        #pragma unroll
        for (int ni = 0; ni < 4; ++ni)
          Vx[row * 128 + wc + ni * 16 + tl] = f2bf(acc[mi][ni][r]);
      }
    __syncthreads();
    const int b = m0 >> 11, h = c0 >> 7;
    const int d = tid >> 1, th = (tid & 1) * 64;
    uint16_t* dst = Vt + (((size_t)(b * 8 + h) * 128 + d) * 2048) + (m0 & 2047) + th;
    #pragma unroll
    for (int cc = 0; cc < 8; ++cc) {
      bf8 v;
      #pragma unroll
      for (int j = 0; j < 8; ++j) v[j] = Vx[(th + cc * 8 + j) * 128 + d];
      *(bf8*)&dst[cc * 8] = v;
    }
  }
}

// ---------- GEMM v5 (256x256, BK=64, 8-phase schedule) — unchanged ----------
template<bool OF32>
__global__ __launch_bounds__(512, 2)
void eagle3_gemm5(const uint16_t* __restrict__ Ap, const uint16_t* __restrict__ Bp,
                  void* __restrict__ Cp, int K, int lda, int ldb, int ldc)
{
  __shared__ __align__(16) uint16_t As[2][2][128 * 64];
  __shared__ __align__(16) uint16_t Bs[2][2][128 * 64];

  int bx, by;
  const int bid = blockIdx.y * gridDim.x + blockIdx.x;
  if (gridDim.x == 16 && gridDim.y == 16) {
    const int x = bid & 7, j = bid >> 3;
    by = (x >> 1) * 4 + (j >> 3);
    bx = (x & 1) * 8 + (j & 7);
  } else {
    const int nwg = gridDim.x * gridDim.y;
    const int qq = nwg >> 3;
    const int sw = (bid & 7) * qq + (bid >> 3);
    bx = sw % gridDim.x; by = sw / gridDim.x;
  }
  const int m0 = by * 256, n0 = bx * 256;

  const int tid = threadIdx.x, lane = tid & 63;
  const int tl = lane & 15, g = lane >> 4;
  const int w = tid >> 6;
  const int wm = w >> 2, wn = w & 3;
  const int bhf = wn >> 1;
  const int bl0 = (wn & 1) * 64;

  f4 acc[8][4] = {};
  const int NI = K >> 7;

  const int jr = tid >> 3;
  const int jc = ((tid & 7) ^ (jr & 7)) * 8;
  #define STG_A(slot, h, tt)                                                    \
    { const int kk_ = (tt) << 6;                                                \
      gload_lds16(Ap + (size_t)(m0 + (h)*128 + jr) * lda + kk_ + jc,            \
                  &As[slot][h][tid * 8]);                                       \
      gload_lds16(Ap + (size_t)(m0 + (h)*128 + 64 + jr) * lda + kk_ + jc,       \
                  &As[slot][h][(tid + 512) * 8]); }
  #define STG_B(slot, h, tt)                                                    \
    { const int kk_ = (tt) << 6;                                                \
      gload_lds16(Bp + (size_t)(n0 + (h)*128 + jr) * ldb + kk_ + jc,            \
                  &Bs[slot][h][tid * 8]);                                       \
      gload_lds16(Bp + (size_t)(n0 + (h)*128 + 64 + jr) * ldb + kk_ + jc,       \
                  &Bs[slot][h][(tid + 512) * 8]); }

  const int rk0 = ((0 + g) ^ (tl & 7)) * 8;
  const int rk1 = ((4 + g) ^ (tl & 7)) * 8;

  bf8 af[8], b0[4], b1[4];
  #define READ_A(slot, rh)                                                      \
    { _Pragma("unroll")                                                         \
      for (int m_ = 0; m_ < 4; ++m_) {                                          \
        const int R_ = (rh)*64 + m_*16 + tl;                                    \
        af[m_*2]   = *(const bf8*)&As[slot][wm][R_*64 + rk0];                   \
        af[m_*2+1] = *(const bf8*)&As[slot][wm][R_*64 + rk1];                   \
      } }
  #define READ_B(slot, ch, dst)                                                 \
    { _Pragma("unroll")                                                         \
      for (int c_ = 0; c_ < 2; ++c_) {                                          \
        const int R_ = bl0 + (ch)*32 + c_*16 + tl;                              \
        dst[c_*2]   = *(const bf8*)&Bs[slot][bhf][R_*64 + rk0];                 \
        dst[c_*2+1] = *(const bf8*)&Bs[slot][bhf][R_*64 + rk1];                 \
      } }
  #define MID_SYNC                                                              \
    __builtin_amdgcn_sched_barrier(0);                                          \
    __builtin_amdgcn_s_barrier();                                               \
    asm volatile("s_waitcnt lgkmcnt(0)" ::: "memory");                          \
    __builtin_amdgcn_sched_barrier(0);
  #define CLOSE_BAR                                                             \
    __builtin_amdgcn_sched_barrier(0);                                          \
    __builtin_amdgcn_s_barrier();                                               \
    __builtin_amdgcn_sched_barrier(0);
  #define MFMA16(rh, ch, bsrc)                                                  \
    { __builtin_amdgcn_s_setprio(1);                                            \
      _Pragma("unroll")                                                         \
      for (int m_ = 0; m_ < 4; ++m_) {                                          \
        _Pragma("unroll")                                                       \
        for (int c_ = 0; c_ < 2; ++c_) {                                        \
          acc[(rh)*4+m_][(ch)*2+c_] = __builtin_amdgcn_mfma_f32_16x16x32_bf16(  \
              af[m_*2],   bsrc[c_*2],   acc[(rh)*4+m_][(ch)*2+c_], 0, 0, 0);    \
          acc[(rh)*4+m_][(ch)*2+c_] = __builtin_amdgcn_mfma_f32_16x16x32_bf16(  \
              af[m_*2+1], bsrc[c_*2+1], acc[(rh)*4+m_][(ch)*2+c_], 0, 0, 0);    \
        } }                                                                     \
      __builtin_amdgcn_s_setprio(0); }

  STG_A(0, 0, 0); STG_A(0, 1, 0); STG_B(0, 0, 0); STG_B(0, 1, 0);
  STG_B(1, 0, 1); STG_B(1, 1, 1);
  asm volatile("s_waitcnt vmcnt(4)" ::: "memory");
  CLOSE_BAR;
  READ_B(0, 0, b0);

  for (int i = 0; i < NI; ++i) {
    const int T1 = 2 * i + 1;
    const bool more = (i + 1 < NI);

    READ_A(0, 0);
    STG_A(1, 0, T1);
    MID_SYNC; MFMA16(0, 0, b0); CLOSE_BAR;

    READ_B(0, 1, b1);
    STG_A(1, 1, T1);
    MID_SYNC; MFMA16(0, 1, b1); CLOSE_BAR;

    READ_A(0, 1);
    if (more) STG_B(0, 0, T1 + 1);
    MID_SYNC; MFMA16(1, 0, b0);
    if (more) { asm volatile("s_waitcnt vmcnt(6)" ::: "memory"); }
    else      { asm volatile("s_waitcnt vmcnt(4)" ::: "memory"); }
    CLOSE_BAR;

    READ_B(1, 0, b0);
    if (more) STG_B(0, 1, T1 + 1);
    MID_SYNC; MFMA16(1, 1, b1);
    if (more) { asm volatile("s_waitcnt vmcnt(4)" ::: "memory"); }
    else      { asm volatile("s_waitcnt vmcnt(0)" ::: "memory"); }
    CLOSE_BAR;

    READ_A(1, 0);
    if (more) STG_A(0, 0, T1 + 1);
    MID_SYNC; MFMA16(0, 0, b0); CLOSE_BAR;

    READ_B(1, 1, b1);
    if (more) STG_A(0, 1, T1 + 1);
    MID_SYNC; MFMA16(0, 1, b1); CLOSE_BAR;

    READ_A(1, 1);
    if (more) STG_B(1, 0, T1 + 2);
    MID_SYNC; MFMA16(1, 0, b0);
    if (more) { asm volatile("s_waitcnt vmcnt(6)" ::: "memory"); }
    CLOSE_BAR;

    if (more) { READ_B(0, 0, b0); STG_B(1, 1, T1 + 2); }
    MID_SYNC; MFMA16(1, 1, b1);
    if (more) { asm volatile("s_waitcnt vmcnt(4)" ::: "memory"); }
    CLOSE_BAR;
  }
  #undef STG_A
  #undef STG_B
  #undef READ_A
  #undef READ_B
  #undef MID_SYNC
  #undef CLOSE_BAR
  #undef MFMA16

  const int wr = wm * 128, wc = wn * 64;
  #pragma unroll
  for (int mi = 0; mi < 8; ++mi) {
    #pragma unroll
    for (int r = 0; r < 4; ++r) {
      const int row = m0 + wr + mi * 16 + g * 4 + r;
      #pragma unroll
      for (int ni = 0; ni < 4; ++ni) {
        const int col = n0 + wc + ni * 16 + tl;
        const float v = acc[mi][ni][r];
        if constexpr (OF32) ((float*)Cp)[(size_t)row * ldc + col] = v;
        else                ((uint16_t*)Cp)[(size_t)row * ldc + col] = f2bf(v);
      }
    }
  }
}

// ---------- causal GQA flash attention v8 (unchanged) ----------
__global__ __launch_bounds__(512, 4)
void eagle3_flash8(const uint16_t* __restrict__ Q, const uint16_t* __restrict__ Kt,
                   const uint16_t* __restrict__ Vt, uint16_t* __restrict__ O,
                   const float* __restrict__ Cst, const float* __restrict__ Snt)
{
  __shared__ __align__(16) uint16_t Ks[2][64 * 128];   // 32 KB
  __shared__ __align__(16) uint16_t Vs[2][128 * 64];   // 32 KB
  __shared__ __align__(16) uint16_t Pl[8][16 * 64];    // 16 KB (per-wave, swz)

  const int tid = threadIdx.x, lane = tid & 63, w = tid >> 6;
  const int tl = lane & 15, g = lane >> 4;

  const int bid = (int)blockIdx.x + ((int)blockIdx.y << 4) + ((int)blockIdx.z << 9);
  const int xcd = bid & 7, idx = bid >> 3;
  const int grp = xcd * 2 + (idx >> 6);
  const int j   = idx & 63;
  const int b = grp >> 3, hkv = grp & 7;
  const int hq = hkv * 4 + (j & 3);
  const int qt = 15 - (j >> 2);
  const int qrow0 = qt * 128 + w * 16;
  const int ntb = 2 * qt + 2;

  bf8 qf[4];
  {
    const int srow = qrow0 + tl;
    const uint16_t* qp = Q + ((size_t)(b * 2048 + srow)) * 4096 + hq * 128 + g * 8;
    #pragma unroll
    for (int kb = 0; kb < 4; ++kb) qf[kb] = *(const bf8*)(qp + kb * 32);
    const float* cp = Cst + (size_t)srow * 128 + g * 8;
    const float* sp = Snt + (size_t)srow * 128 + g * 8;
    #pragma unroll
    for (int kb = 0; kb < 2; ++kb) {
      const float4 c0 = *(const float4*)(cp + kb * 32);
      const float4 c1 = *(const float4*)(cp + kb * 32 + 4);
      const float4 s0 = *(const float4*)(sp + kb * 32);
      const float4 s1 = *(const float4*)(sp + kb * 32 + 4);
      const float cc[8] = {c0.x,c0.y,c0.z,c0.w,c1.x,c1.y,c1.z,c1.w};
      const float ss[8] = {s0.x,s0.y,s0.z,s0.w,s1.x,s1.y,s1.z,s1.w};
      #pragma unroll
      for (int e = 0; e < 8; ++e) {
        const float x1 = bf2f((uint16_t)qf[kb][e]);
        const float x2 = bf2f((uint16_t)qf[kb + 2][e]);
        qf[kb][e]     = (short)f2bf(x1 * cc[e] - x2 * ss[e]);
        qf[kb + 2][e] = (short)f2bf(x2 * cc[e] + x1 * ss[e]);
      }
    }
  }

  const uint16_t* Kbase = Kt + (size_t)b * 2048 * 1024 + hkv * 128;
  const uint16_t* Vtb   = Vt + ((size_t)(b * 8 + hkv) * 128) * 2048;

  bf8 onesf = {};
  if (tl == 0) {
    #pragma unroll
    for (int q8 = 0; q8 < 8; ++q8) onesf[q8] = (short)0x3F80;
  }

  f4 acc[8] = {};
  f4 accl = {};
  float rm[4] = {-3e38f, -3e38f, -3e38f, -3e38f};
  const float KS = 0.1275174f;                // log2(e)/sqrt(128)
  const float DEFER = 90.5f;                  // 8 nats in raw-score units

  #define STAGE_TILE(buf, t0s)                                                   \
    {                                                                            \
      _Pragma("unroll")                                                          \
      for (int i = 0; i < 2; ++i) {                                              \
        const int f = i * 512 + tid;                                             \
        const int r = f >> 4, c = f & 15;                                        \
        gload_lds16(Kbase + (size_t)((t0s) + r) * 1024 + ((c ^ (r & 7)) * 8),    \
                    &Ks[buf][(i * 512 + w * 64) * 8]);                           \
      }                                                                          \
      _Pragma("unroll")                                                          \
      for (int i = 0; i < 2; ++i) {                                              \
        const int f = i * 512 + tid;                                             \
        const int d = f >> 3, c = f & 7;                                         \
        gload_lds16(Vtb + (size_t)d * 2048 + (t0s) + ((c ^ (d & 7)) * 8),        \
                    &Vs[buf][(i * 512 + w * 64) * 8]);                           \
      }                                                                          \
    }

  STAGE_TILE(0, 0);

  for (int tb = 0; tb < ntb; ++tb) {
    const int cur = tb & 1;
    const int t0 = tb * 64;

    if (tb + 1 < ntb) {
      STAGE_TILE(cur ^ 1, t0 + 64);
      asm volatile("s_waitcnt vmcnt(4)" ::: "memory");
    } else {
      asm volatile("s_waitcnt vmcnt(0)" ::: "memory");
    }
    __builtin_amdgcn_sched_barrier(0);
    __builtin_amdgcn_s_barrier();

    const bool active = (t0 <= qrow0 + 15);
    if (active) {
      f4 s[4] = {};
      __builtin_amdgcn_s_setprio(1);
      #pragma unroll
      for (int cf = 0; cf < 4; ++cf) {
        #pragma unroll
        for (int kb = 0; kb < 4; ++kb) {
          const bf8 kf = *(const bf8*)&Ks[cur][(cf * 16 + tl) * 128 +
                                              (((kb * 4 + g) ^ (tl & 7)) * 8)];
          s[cf] = __builtin_amdgcn_mfma_f32_16x16x32_bf16(qf[kb], kf, s[cf], 0, 0, 0);
        }
      }
      __builtin_amdgcn_s_setprio(0);

      const bool edge = (t0 + 63 > qrow0);
      float p[4][4];
      #pragma unroll
      for (int r = 0; r < 4; ++r) {
        float v[4];
        #pragma unroll
        for (int cf = 0; cf < 4; ++cf) v[cf] = s[cf][r];
        if (edge) {
          const int qg = qrow0 + g * 4 + r;
          #pragma unroll
          for (int cf = 0; cf < 4; ++cf)
            if (t0 + cf * 16 + tl > qg) v[cf] = -3e38f;
        }
        float mx = fmaxf(fmaxf(v[0], v[1]), fmaxf(v[2], v[3]));
        mx = fmaxf(mx, __shfl_xor(mx, 1));
        mx = fmaxf(mx, __shfl_xor(mx, 2));
        mx = fmaxf(mx, __shfl_xor(mx, 4));
        mx = fmaxf(mx, __shfl_xor(mx, 8));
        if (mx > rm[r] + DEFER) {
          const float corr = exp2f((rm[r] - mx) * KS);
          #pragma unroll
          for (int df = 0; df < 8; ++df) acc[df][r] *= corr;
          accl[r] *= corr;
          rm[r] = mx;
        }
        #pragma unroll
        for (int cf = 0; cf < 4; ++cf) p[r][cf] = exp2f((v[cf] - rm[r]) * KS);
      }

      #pragma unroll
      for (int r = 0; r < 4; ++r) {
        const uint32_t pk0 = cvtpk(p[r][0], p[r][1]);
        const uint32_t pk1 = cvtpk(p[r][2], p[r][3]);
        const int row = g * 4 + r;
        const int sw = row & 7;
        uint16_t* Pw = &Pl[w][row * 64 + (tl & 7)];
        Pw[(((tl >> 3) + 0) ^ sw) * 8] = (uint16_t)pk0;
        Pw[(((tl >> 3) + 2) ^ sw) * 8] = (uint16_t)(pk0 >> 16);
        Pw[(((tl >> 3) + 4) ^ sw) * 8] = (uint16_t)pk1;
        Pw[(((tl >> 3) + 6) ^ sw) * 8] = (uint16_t)(pk1 >> 16);
      }
      const bf8 pf0 = *(const bf8*)&Pl[w][tl * 64 + ((g ^ (tl & 7)) * 8)];
      const bf8 pf1 = *(const bf8*)&Pl[w][tl * 64 + (((4 + g) ^ (tl & 7)) * 8)];

      __builtin_amdgcn_s_setprio(1);
      accl = __builtin_amdgcn_mfma_f32_16x16x32_bf16(pf0, onesf, accl, 0, 0, 0);
      accl = __builtin_amdgcn_mfma_f32_16x16x32_bf16(pf1, onesf, accl, 0, 0, 0);
      #pragma unroll
      for (int df = 0; df < 8; ++df) {
        const int vrow = (df * 16 + tl) * 64;
        const bf8 v0 = *(const bf8*)&Vs[cur][vrow + ((g ^ (tl & 7)) * 8)];
        const bf8 v1 = *(const bf8*)&Vs[cur][vrow + (((4 + g) ^ (tl & 7)) * 8)];
        acc[df] = __builtin_amdgcn_mfma_f32_16x16x32_bf16(pf0, v0, acc[df], 0, 0, 0);
        acc[df] = __builtin_amdgcn_mfma_f32_16x16x32_bf16(pf1, v1, acc[df], 0, 0, 0);
      }
      __builtin_amdgcn_s_setprio(0);
    }

    __builtin_amdgcn_s_barrier();
  }
  #undef STAGE_TILE

  #pragma unroll
  for (int r = 0; r < 4; ++r) {
    const float l = __shfl(accl[r], lane & 48);
    const float inv = 1.0f / l;
    const size_t ob = ((size_t)(b * 2048 + qrow0 + g * 4 + r)) * 4096 + hq * 128 + tl;
    #pragma unroll
    for (int df = 0; df < 8; ++df)
      O[ob + df * 16] = f2bf(acc[df][r] * inv);
  }
}

// ---------- launch ----------
extern "C" void kernel_launch(void* const* d_in, const int* in_sizes, int n_in,
                              void* d_out, int out_size, void* d_ws, size_t ws_size,
                              hipStream_t stream) {
  const float* hs   = (const float*)d_in[0];
  const float* cosT = (const float*)d_in[2];
  const float* sinT = (const float*)d_in[3];
  const float* Wq   = (const float*)d_in[4];
  const float* Wk   = (const float*)d_in[5];
  const float* Wv   = (const float*)d_in[6];
  const float* Wo   = (const float*)d_in[7];

  // ---- workspace liveness (ws >= 112 MiB, proven) ----
  // hsb = d_out [4096,8192] bf16 (64MB)   live: cvt2 -> KV gemm
  // [  0M, 32M) qb    live: Q gemm -> flash
  // [ 32M, 40M) kbuf  live: KV gemm (rope fused) -> flash
  // [ 40M, 48M) vt    live: KV gemm (V-transpose epilogue) -> flash
  //                   (disjoint from wkv -- aliasing it was the r17/18 bug)
  // [ 48M, 80M) wkv   Wq bf16 first (dead after Q gemm), then [Wk;Wv]
  // [ 48M, 80M) ctx   live: flash -> Wo gemm (over dead wkv)
  // [ 80M,112M) wobf  live: cvt3 -> Wo gemm
  char* ws = (char*)d_ws;
  uint16_t* qb   = (uint16_t*)(ws);
  uint16_t* kbuf = (uint16_t*)(ws + 33554432);
  uint16_t* vt   = (uint16_t*)(ws + 41943040);
  uint16_t* wkv  = (uint16_t*)(ws + 50331648);
  uint16_t* ctx  = (uint16_t*)(ws + 50331648);
  uint16_t* wobf = (uint16_t*)(ws + 83886080);
  uint16_t* hsb  = (uint16_t*)d_out;

  const dim3 blk(256);

  // 1) hs + Wq f32 -> bf16 in one launch
  eagle3_cvt2<<<dim3(2048), blk, 0, stream>>>(hs, hsb, 4194304, Wq, wkv, 4194304);

  // 2) Q projection (Wq bf16 at [48M,112M), dead after this gemm)
  eagle3_gemm5<false><<<dim3(16, 16), dim3(512), 0, stream>>>(
      hsb, wkv, (void*)qb, 8192, 8192, 8192, 4096);

  // 3) remaining weights in ONE cvt: [Wk;Wv] -> [48M,80M), Wo -> [80M,112M)
  eagle3_cvt3<<<dim3(2048), blk, 0, stream>>>(
      Wk, wkv, 1048576, Wv, wkv + 8388608, 1048576, Wo, wobf, 2097152);

  // 4) fused K/V projection via 4-ring; K gets RoPE, V written transposed
  eagle3_gemm7<<<dim3(16, 32), blk, 0, stream>>>(
      hsb, wkv, kbuf, vt, cosT, sinT);

  // 5) causal GQA flash attention (in-register Q RoPE, defer-max) -> ctx
  eagle3_flash8<<<dim3(16, 32, 2), dim3(512), 0, stream>>>(
      qb, kbuf, vt, ctx, cosT, sinT);

  // 6) output projection: out = ctx * Wo^T (f32 out over dead hsb)
  eagle3_gemm5<true><<<dim3(16, 16), dim3(512), 0, stream>>>(
      ctx, wobf, d_out, 4096, 4096, 4096, 4096);
}